// Round 4
// baseline (554.791 us; speedup 1.0000x reference)
//
#include <hip/hip_runtime.h>

#define S_    2048
#define N_    16
#define OBS_  8
#define PRED_ 12
#define B_    (S_*N_)

__device__ __forceinline__ float4 ld4(const float* p) { return *(const float4*)p; }
__device__ __forceinline__ float sigmf(float x) { return __builtin_amdgcn_rcpf(1.0f + __expf(-x)); }
__device__ __forceinline__ float tanhx(float x) { return fmaf(-2.0f, __builtin_amdgcn_rcpf(1.0f + __expf(2.0f*x)), 1.0f); }

__device__ __forceinline__ float dot16w(const float* w, const float4 x0, const float4 x1,
                                        const float4 x2, const float4 x3) {
  float4 w0 = ld4(w); float4 w1 = ld4(w+4); float4 w2 = ld4(w+8); float4 w3 = ld4(w+12);
  float a = x0.x*w0.x + x0.y*w0.y + x0.z*w0.z + x0.w*w0.w;
  float b = x1.x*w1.x + x1.y*w1.y + x1.z*w1.z + x1.w*w1.w;
  float c = x2.x*w2.x + x2.y*w2.y + x2.z*w2.z + x2.w*w2.w;
  float d = x3.x*w3.x + x3.y*w3.y + x3.z*w3.z + x3.w*w3.w;
  return (a+b)+(c+d);
}

// one scene per block; thread (i = agent, k = hidden unit), 256 threads.
// Wave w owns agents 4w..4w+3: h/e/ctx/prev/pos(own row) accesses are intra-wave
// (in-order DS pipe) -> barrier-free. Only hW_s/re_s (pool, cross-wave j) and
// pos_s (cross-agent rel) need barriers: 2 per decoder step, 0 in encoder.
extern "C" __global__ __launch_bounds__(256, 3) void traj_ar_kernel(
    const float* __restrict__ traj_rel, const float* __restrict__ obs_pos,
    const int*  __restrict__ nei,       const float* __restrict__ noise,
    const float* __restrict__ eeW, const float* __restrict__ eeb,
    const float* __restrict__ eWi, const float* __restrict__ eWh, const float* __restrict__ eb,
    const float* __restrict__ diW, const float* __restrict__ dib,
    const float* __restrict__ dWi, const float* __restrict__ dWh, const float* __restrict__ db,
    const float* __restrict__ prW, const float* __restrict__ prb,
    const float* __restrict__ mW,  const float* __restrict__ mb,
    const float* __restrict__ oW,  const float* __restrict__ ob,
    float* __restrict__ out)
{
  // LSTM weights transposed, row stride 20 floats (80B: b128-aligned, 2-way alias = free)
  __shared__ __align__(16) float sW_ee[32];
  __shared__ __align__(16) float sb_ee[16];
  __shared__ __align__(16) float sW_eiT[64*20];
  __shared__ __align__(16) float sW_ehT[64*20];
  __shared__ __align__(16) float sb_e[64];
  __shared__ __align__(16) float sW_diT[16*20];
  __shared__ __align__(16) float sb_di[16];
  __shared__ __align__(16) float sW_dWiT[64*20];
  __shared__ __align__(16) float sW_dWhT[64*20];
  __shared__ __align__(16) float sb_d[64];
  __shared__ __align__(16) float sW_pr[32];
  __shared__ __align__(16) float sb_pr[16];
  __shared__ __align__(16) float sW_o[64];
  __shared__ __align__(16) float sb_o[4];
  // state (h single-buffered: within a wave, all reads issue before the write in
  // program order, and same-wave DS ops complete in order)
  __shared__ __align__(16) float h_s[256];
  __shared__ __align__(16) float e_s[256];
  __shared__ __align__(16) float ctx_s[256];
  __shared__ __align__(16) float hW_s[256];
  // re_s[i][j][m]: j-stride 20 floats (80B) -> phase-3 float4 store start banks
  // cover all multiples of 4, 2 words/bank = free (m136); R1's 64B stride was
  // 8-way on banks {0,16} (1.0e7 conflict cycles). i-stride 324 (1296B, 16B-aligned).
  __shared__ __align__(16) float re_s[16*324];
  __shared__ __align__(16) float pos_s[32];
  __shared__ __align__(16) float prev_s[32];

  const int tid = threadIdx.x;
  const int s = blockIdx.x;
  const int i = tid >> 4;
  const int k = tid & 15;
  const int bi = s*N_ + i;

  // ---- stage weights into LDS ----
  if (tid < 32) sW_ee[tid] = eeW[tid];
  if (tid < 16) sb_ee[tid] = eeb[tid];
  for (int idx = tid; idx < 1024; idx += 256) {
    int m = idx >> 6, c = idx & 63;
    sW_eiT[c*20+m] = eWi[idx];
    sW_ehT[c*20+m] = eWh[idx];
    sW_dWiT[c*20+m] = dWi[idx];
    sW_dWhT[c*20+m] = dWh[idx];
  }
  if (tid < 64) sb_e[tid] = eb[tid];
  for (int idx = tid; idx < 288; idx += 256) { int m = idx >> 4, c = idx & 15; sW_diT[c*20+m] = diW[idx]; }
  if (tid < 16) sb_di[tid] = dib[tid];
  if (tid < 64) sb_d[tid] = db[tid];
  if (tid < 32) sW_pr[tid] = prW[tid];
  if (tid < 16) sb_pr[tid] = prb[tid];
  if (tid < 64) sW_o[tid] = oW[tid];
  if (tid < 4)  sb_o[tid] = ob[tid];

  h_s[tid] = 0.0f;
  ctx_s[tid] = 0.0f;
  if (k < 2) {
    prev_s[i*2+k] = traj_rel[((OBS_-1)*B_ + bi)*2 + k];  // out init = traj_rel[OBS-1]
    pos_s[i*2+k]  = obs_pos[((OBS_-1)*B_ + bi)*2 + k];   // pos init = obs_traj_pos[-1]
  }

  // pool-MLP column k in registers (32 floats); all blocks hit the same L1/L2 lines
  float wm[32];
  #pragma unroll
  for (int m = 0; m < 32; ++m) wm[m] = mW[m*16 + k];
  const float bmlp = mb[k];

  // time-invariant neighbor mask -> register bitmask via wave ballot
  unsigned long long bal = __ballot(nei[bi*N_ + k] > 0);
  const unsigned mbits = (unsigned)((bal >> (16*(i & 3))) & 0xFFFFull);
  const bool has = (mbits != 0);

  __syncthreads();

  // ---- encoder: 8 LSTM steps, zero barriers (h rows wave-private) ----
  float c_reg = 0.0f;
  const float2* xr2 = (const float2*)traj_rel;
  for (int t = 0; t < OBS_; ++t) {
    float2 x = xr2[t*B_ + bi];
    float em[16];
    #pragma unroll
    for (int m = 0; m < 16; ++m)
      em[m] = fmaxf(fmaf(x.y, sW_ee[16+m], fmaf(x.x, sW_ee[m], sb_ee[m])), 0.0f);
    float4 e0 = make_float4(em[0],em[1],em[2],em[3]);
    float4 e1 = make_float4(em[4],em[5],em[6],em[7]);
    float4 e2 = make_float4(em[8],em[9],em[10],em[11]);
    float4 e3 = make_float4(em[12],em[13],em[14],em[15]);
    const float* hp = &h_s[i*16];
    float4 h0 = ld4(hp), h1 = ld4(hp+4), h2 = ld4(hp+8), h3 = ld4(hp+12);
    float g0 = sb_e[k]    + dot16w(&sW_eiT[(k)*20],    e0,e1,e2,e3) + dot16w(&sW_ehT[(k)*20],    h0,h1,h2,h3);
    float g1 = sb_e[k+16] + dot16w(&sW_eiT[(k+16)*20], e0,e1,e2,e3) + dot16w(&sW_ehT[(k+16)*20], h0,h1,h2,h3);
    float g2 = sb_e[k+32] + dot16w(&sW_eiT[(k+32)*20], e0,e1,e2,e3) + dot16w(&sW_ehT[(k+32)*20], h0,h1,h2,h3);
    float g3 = sb_e[k+48] + dot16w(&sW_eiT[(k+48)*20], e0,e1,e2,e3) + dot16w(&sW_ehT[(k+48)*20], h0,h1,h2,h3);
    float ig = sigmf(g0), fg = sigmf(g1), gv = tanhx(g2), og = sigmf(g3);
    c_reg = fg*c_reg + ig*gv;
    float nh = og * tanhx(c_reg);
    h_s[i*16+k] = nh;   // all lanes' reads issued above in program order
  }

  // ---- decoder: 12 autoregressive steps, 2 barriers/step ----
  c_reg = 0.0f;
  const int MU_OFF = PRED_*B_*2;
  const int SD_OFF = 2*PRED_*B_*2;
  for (int t = 0; t < PRED_; ++t) {
    // phase 1: e = relu([ctx, prev] @ dec_in_W + b)   (ctx/prev wave-private)
    {
      const float* cx = &ctx_s[i*16];
      float4 c0 = ld4(cx), c1 = ld4(cx+4), c2 = ld4(cx+8), c3 = ld4(cx+12);
      float p0 = prev_s[i*2+0], p1 = prev_s[i*2+1];
      const float* wd = &sW_diT[k*20];
      float acc = sb_di[k] + dot16w(wd, c0,c1,c2,c3) + p0*wd[16] + p1*wd[17];
      e_s[i*16+k] = fmaxf(acc, 0.0f);
    }
    // phase 2: LSTM cell (e/h wave-private)
    {
      const float* ep = &e_s[i*16];
      float4 e0 = ld4(ep), e1 = ld4(ep+4), e2 = ld4(ep+8), e3 = ld4(ep+12);
      const float* hp = &h_s[i*16];
      float4 h0 = ld4(hp), h1 = ld4(hp+4), h2 = ld4(hp+8), h3 = ld4(hp+12);
      float g0 = sb_d[k]    + dot16w(&sW_dWiT[(k)*20],    e0,e1,e2,e3) + dot16w(&sW_dWhT[(k)*20],    h0,h1,h2,h3);
      float g1 = sb_d[k+16] + dot16w(&sW_dWiT[(k+16)*20], e0,e1,e2,e3) + dot16w(&sW_dWhT[(k+16)*20], h0,h1,h2,h3);
      float g2 = sb_d[k+32] + dot16w(&sW_dWiT[(k+32)*20], e0,e1,e2,e3) + dot16w(&sW_dWhT[(k+32)*20], h0,h1,h2,h3);
      float g3 = sb_d[k+48] + dot16w(&sW_dWiT[(k+48)*20], e0,e1,e2,e3) + dot16w(&sW_dWhT[(k+48)*20], h0,h1,h2,h3);
      float ig = sigmf(g0), fg = sigmf(g1), gv = tanhx(g2), og = sigmf(g3);
      c_reg = fg*c_reg + ig*gv;
      float nh = og * tanhx(c_reg);
      h_s[i*16+k] = nh;
    }
    // phase 3: (a) hW[i][k] = h[i] . Wmlp[16:32, k] (own rows, intra-wave)
    //          (b) re[i][j=k][:] embedding (pos from prev step, barrier E covers)
    {
      const float* hj = &h_s[i*16];
      float hw = 0.0f;
      #pragma unroll
      for (int m = 0; m < 16; ++m) hw = fmaf(hj[m], wm[16+m], hw);
      hW_s[i*16+k] = hw;

      float rx = pos_s[i*2+0] - pos_s[k*2+0];
      float ry = pos_s[i*2+1] - pos_s[k*2+1];
      float rv[16];
      #pragma unroll
      for (int m = 0; m < 16; ++m)
        rv[m] = fmaxf(fmaf(ry, sW_pr[16+m], fmaf(rx, sW_pr[m], sb_pr[m])), 0.0f);
      float* rp = &re_s[i*324 + k*20];
      *(float4*)(rp+0)  = make_float4(rv[0],rv[1],rv[2],rv[3]);
      *(float4*)(rp+4)  = make_float4(rv[4],rv[5],rv[6],rv[7]);
      *(float4*)(rp+8)  = make_float4(rv[8],rv[9],rv[10],rv[11]);
      *(float4*)(rp+12) = make_float4(rv[12],rv[13],rv[14],rv[15]);
    }
    __syncthreads(); // B: hW_s/re_s written by all waves before pool reads them
    // phase 4: masked max-pool over neighbors j (re_s reads broadcast across the 16-lane group)
    {
      float pooled = -1e30f;
      const float* rb = &re_s[i*324];
      #pragma unroll
      for (int j = 0; j < 16; ++j) {
        const float* rp = rb + j*20;
        float4 r0 = ld4(rp), r1 = ld4(rp+4), r2 = ld4(rp+8), r3 = ld4(rp+12);
        float acc = bmlp + hW_s[j*16+k];
        acc += r0.x*wm[0]  + r0.y*wm[1]  + r0.z*wm[2]  + r0.w*wm[3]
             + r1.x*wm[4]  + r1.y*wm[5]  + r1.z*wm[6]  + r1.w*wm[7]
             + r2.x*wm[8]  + r2.y*wm[9]  + r2.z*wm[10] + r2.w*wm[11]
             + r3.x*wm[12] + r3.y*wm[13] + r3.z*wm[14] + r3.w*wm[15];
        float feat = fmaxf(acc, 0.0f);
        if ((mbits >> j) & 1u) pooled = fmaxf(pooled, feat);
      }
      ctx_s[i*16+k] = has ? pooled : 0.0f;   // wave-private row
    }
    // phase 5: o4 = (h+ctx)@out_W + b; mu/std/pred; outputs; advance pos/prev
    {
      float o4v = 0.0f;
      if (k < 4) {
        const float* hp = &h_s[i*16];
        const float* cx = &ctx_s[i*16];
        float acc = sb_o[k];
        #pragma unroll
        for (int m = 0; m < 16; ++m) acc = fmaf(hp[m]+cx[m], sW_o[m*4+k], acc);
        o4v = acc;
      }
      float sc = __shfl_down(o4v, 2, 64);   // lane k<2 grabs o4[2+k]
      if (k < 2) {
        float mu = o4v;
        float scale = fminf(fmaxf(sc, -9.0f), 4.0f);
        float sd = __expf(scale);
        float nz = noise[(t*B_ + bi)*2 + k];
        float pr = fmaf(sd, nz, mu);
        int o = (t*B_ + bi)*2 + k;
        out[o]          = pr;
        out[MU_OFF + o] = mu;
        out[SD_OFF + o] = sd;
        pos_s[i*2+k] += pr;
        prev_s[i*2+k] = pr;
      }
    }
    __syncthreads(); // E: pos_s cross-agent for next step's phase 3
  }
}

extern "C" void kernel_launch(void* const* d_in, const int* in_sizes, int n_in,
                              void* d_out, int out_size, void* d_ws, size_t ws_size,
                              hipStream_t stream) {
  (void)in_sizes; (void)n_in; (void)d_ws; (void)ws_size; (void)out_size;
  traj_ar_kernel<<<dim3(S_), dim3(256), 0, stream>>>(
      (const float*)d_in[0],  (const float*)d_in[1],  (const int*)d_in[2],   (const float*)d_in[3],
      (const float*)d_in[4],  (const float*)d_in[5],  (const float*)d_in[6], (const float*)d_in[7],
      (const float*)d_in[8],  (const float*)d_in[9],  (const float*)d_in[10],(const float*)d_in[11],
      (const float*)d_in[12], (const float*)d_in[13], (const float*)d_in[14],(const float*)d_in[15],
      (const float*)d_in[16], (const float*)d_in[17], (const float*)d_in[18],(const float*)d_in[19],
      (float*)d_out);
}

// Round 5
// 317.606 us; speedup vs baseline: 1.7468x; 1.7468x over previous
//
#include <hip/hip_runtime.h>

#define S_    2048
#define N_    16
#define OBS_  8
#define PRED_ 12
#define B_    (S_*N_)

__device__ __forceinline__ float4 ld4(const float* p) { return *(const float4*)p; }
__device__ __forceinline__ float sigmf(float x) { return __builtin_amdgcn_rcpf(1.0f + __expf(-x)); }
__device__ __forceinline__ float tanhx(float x) { return fmaf(-2.0f, __builtin_amdgcn_rcpf(1.0f + __expf(2.0f*x)), 1.0f); }

__device__ __forceinline__ float dot16w(const float* w, const float4 x0, const float4 x1,
                                        const float4 x2, const float4 x3) {
  float4 w0 = ld4(w); float4 w1 = ld4(w+4); float4 w2 = ld4(w+8); float4 w3 = ld4(w+12);
  float a = x0.x*w0.x + x0.y*w0.y + x0.z*w0.z + x0.w*w0.w;
  float b = x1.x*w1.x + x1.y*w1.y + x1.z*w1.z + x1.w*w1.w;
  float c = x2.x*w2.x + x2.y*w2.y + x2.z*w2.z + x2.w*w2.w;
  float d = x3.x*w3.x + x3.y*w3.y + x3.z*w3.z + x3.w*w3.w;
  return (a+b)+(c+d);
}

// one scene per block; thread (i = agent, k = hidden unit), 256 threads.
// NOTE: keep the R1 barrier structure (5/decoder step). Removing barriers and
// merging phases (R2-R4) made the scheduler extend live ranges across phases,
// demoting arrays to scratch: 700-900 MB HBM fetch + 240-280 MB write of spill
// traffic (scratch working set > 4 MB/XCD L2). Barriers act as scheduling
// fences that keep live ranges short; FETCH was 3.9 MB with them.
extern "C" __global__ __launch_bounds__(256, 3) void traj_ar_kernel(
    const float* __restrict__ traj_rel, const float* __restrict__ obs_pos,
    const int*  __restrict__ nei,       const float* __restrict__ noise,
    const float* __restrict__ eeW, const float* __restrict__ eeb,
    const float* __restrict__ eWi, const float* __restrict__ eWh, const float* __restrict__ eb,
    const float* __restrict__ diW, const float* __restrict__ dib,
    const float* __restrict__ dWi, const float* __restrict__ dWh, const float* __restrict__ db,
    const float* __restrict__ prW, const float* __restrict__ prb,
    const float* __restrict__ mW,  const float* __restrict__ mb,
    const float* __restrict__ oW,  const float* __restrict__ ob,
    float* __restrict__ out)
{
  // weights: LSTM mats transposed, row stride 20 floats (80B: b128-aligned, 2-way bank alias = free)
  __shared__ __align__(16) float sW_ee[32];
  __shared__ __align__(16) float sb_ee[16];
  __shared__ __align__(16) float sW_eiT[64*20];
  __shared__ __align__(16) float sW_ehT[64*20];
  __shared__ __align__(16) float sb_e[64];
  __shared__ __align__(16) float sW_diT[16*20];   // 18 rows used of stride 20
  __shared__ __align__(16) float sb_di[16];
  __shared__ __align__(16) float sW_dWiT[64*20];
  __shared__ __align__(16) float sW_dWhT[64*20];
  __shared__ __align__(16) float sb_d[64];
  __shared__ __align__(16) float sW_pr[32];
  __shared__ __align__(16) float sb_pr[16];
  __shared__ __align__(16) float sW_o[64];
  __shared__ __align__(16) float sb_o[4];
  // state
  __shared__ __align__(16) float h_s[2][256];
  __shared__ __align__(16) float e_s[256];
  __shared__ __align__(16) float ctx_s[256];
  __shared__ __align__(16) float hW_s[256];
  // re_s[i][j][m]: j-stride 20 floats (80B) -> float4 store start banks cover all
  // 8 bank-quads uniformly, exactly 8 words/bank = conflict-free. R1's j-stride 16
  // started only on banks {0,16}: 8-way, 1.02e7 conflict cycles (~6% of runtime).
  __shared__ __align__(16) float re_s[16*324];
  __shared__ __align__(16) float pos_s[32];
  __shared__ __align__(16) float prev_s[32];

  const int tid = threadIdx.x;
  const int s = blockIdx.x;
  const int i = tid >> 4;
  const int k = tid & 15;
  const int bi = s*N_ + i;

  // ---- stage weights into LDS ----
  if (tid < 32) sW_ee[tid] = eeW[tid];
  if (tid < 16) sb_ee[tid] = eeb[tid];
  for (int idx = tid; idx < 1024; idx += 256) {
    int m = idx >> 6, c = idx & 63;
    sW_eiT[c*20+m] = eWi[idx];
    sW_ehT[c*20+m] = eWh[idx];
    sW_dWiT[c*20+m] = dWi[idx];
    sW_dWhT[c*20+m] = dWh[idx];
  }
  if (tid < 64) sb_e[tid] = eb[tid];
  for (int idx = tid; idx < 288; idx += 256) { int m = idx >> 4, c = idx & 15; sW_diT[c*20+m] = diW[idx]; }
  if (tid < 16) sb_di[tid] = dib[tid];
  if (tid < 64) sb_d[tid] = db[tid];
  if (tid < 32) sW_pr[tid] = prW[tid];
  if (tid < 16) sb_pr[tid] = prb[tid];
  if (tid < 64) sW_o[tid] = oW[tid];
  if (tid < 4)  sb_o[tid] = ob[tid];

  h_s[0][tid] = 0.0f;
  ctx_s[tid] = 0.0f;
  if (k < 2) {
    prev_s[i*2+k] = traj_rel[((OBS_-1)*B_ + bi)*2 + k];  // out init = traj_rel[OBS-1]
    pos_s[i*2+k]  = obs_pos[((OBS_-1)*B_ + bi)*2 + k];   // pos init = obs_traj_pos[-1]
  }

  // pool-MLP column k lives in registers (32 floats); all blocks hit same L1 lines
  float wm[32];
  #pragma unroll
  for (int m = 0; m < 32; ++m) wm[m] = mW[m*16 + k];
  const float bmlp = mb[k];

  // time-invariant neighbor mask -> register bitmask via wave ballot
  unsigned long long bal = __ballot(nei[bi*N_ + k] > 0);
  const unsigned mbits = (unsigned)((bal >> (16*(i & 3))) & 0xFFFFull);
  const bool has = (mbits != 0);

  __syncthreads();

  // ---- encoder: 8 LSTM steps ----
  int cur = 0;
  float c_reg = 0.0f;
  const float2* xr2 = (const float2*)traj_rel;
  for (int t = 0; t < OBS_; ++t) {
    float2 x = xr2[t*B_ + bi];
    float em[16];
    #pragma unroll
    for (int m = 0; m < 16; ++m)
      em[m] = fmaxf(fmaf(x.y, sW_ee[16+m], fmaf(x.x, sW_ee[m], sb_ee[m])), 0.0f);
    float4 e0 = make_float4(em[0],em[1],em[2],em[3]);
    float4 e1 = make_float4(em[4],em[5],em[6],em[7]);
    float4 e2 = make_float4(em[8],em[9],em[10],em[11]);
    float4 e3 = make_float4(em[12],em[13],em[14],em[15]);
    const float* hp = &h_s[cur][i*16];
    float4 h0 = ld4(hp), h1 = ld4(hp+4), h2 = ld4(hp+8), h3 = ld4(hp+12);
    float g0 = sb_e[k]    + dot16w(&sW_eiT[(k)*20],    e0,e1,e2,e3) + dot16w(&sW_ehT[(k)*20],    h0,h1,h2,h3);
    float g1 = sb_e[k+16] + dot16w(&sW_eiT[(k+16)*20], e0,e1,e2,e3) + dot16w(&sW_ehT[(k+16)*20], h0,h1,h2,h3);
    float g2 = sb_e[k+32] + dot16w(&sW_eiT[(k+32)*20], e0,e1,e2,e3) + dot16w(&sW_ehT[(k+32)*20], h0,h1,h2,h3);
    float g3 = sb_e[k+48] + dot16w(&sW_eiT[(k+48)*20], e0,e1,e2,e3) + dot16w(&sW_ehT[(k+48)*20], h0,h1,h2,h3);
    float ig = sigmf(g0), fg = sigmf(g1), gv = tanhx(g2), og = sigmf(g3);
    c_reg = fg*c_reg + ig*gv;
    float nh = og * tanhx(c_reg);
    h_s[cur^1][i*16+k] = nh;   // write other buffer: no read/write race
    __syncthreads();
    cur ^= 1;
  }

  // ---- decoder: 12 autoregressive steps ----
  c_reg = 0.0f;                       // decoder c starts at zero
  const int MU_OFF = PRED_*B_*2;
  const int SD_OFF = 2*PRED_*B_*2;
  for (int t = 0; t < PRED_; ++t) {
    // phase 1: e = relu([ctx, prev] @ dec_in_W + b)
    {
      const float* cx = &ctx_s[i*16];
      float4 c0 = ld4(cx), c1 = ld4(cx+4), c2 = ld4(cx+8), c3 = ld4(cx+12);
      float p0 = prev_s[i*2+0], p1 = prev_s[i*2+1];
      const float* wd = &sW_diT[k*20];
      float acc = sb_di[k] + dot16w(wd, c0,c1,c2,c3) + p0*wd[16] + p1*wd[17];
      e_s[i*16+k] = fmaxf(acc, 0.0f);
    }
    __syncthreads(); // A
    // phase 2: LSTM cell
    {
      const float* ep = &e_s[i*16];
      float4 e0 = ld4(ep), e1 = ld4(ep+4), e2 = ld4(ep+8), e3 = ld4(ep+12);
      const float* hp = &h_s[cur][i*16];
      float4 h0 = ld4(hp), h1 = ld4(hp+4), h2 = ld4(hp+8), h3 = ld4(hp+12);
      float g0 = sb_d[k]    + dot16w(&sW_dWiT[(k)*20],    e0,e1,e2,e3) + dot16w(&sW_dWhT[(k)*20],    h0,h1,h2,h3);
      float g1 = sb_d[k+16] + dot16w(&sW_dWiT[(k+16)*20], e0,e1,e2,e3) + dot16w(&sW_dWhT[(k+16)*20], h0,h1,h2,h3);
      float g2 = sb_d[k+32] + dot16w(&sW_dWiT[(k+32)*20], e0,e1,e2,e3) + dot16w(&sW_dWhT[(k+32)*20], h0,h1,h2,h3);
      float g3 = sb_d[k+48] + dot16w(&sW_dWiT[(k+48)*20], e0,e1,e2,e3) + dot16w(&sW_dWhT[(k+48)*20], h0,h1,h2,h3);
      float ig = sigmf(g0), fg = sigmf(g1), gv = tanhx(g2), og = sigmf(g3);
      c_reg = fg*c_reg + ig*gv;
      float nh = og * tanhx(c_reg);
      h_s[cur^1][i*16+k] = nh;
    }
    __syncthreads(); // B
    cur ^= 1;
    // phase 3: (a) hW[j][k] = h[j] . Wmlp[16:32, k]  (this thread's i plays the j role)
    //          (b) re[i][j][:] embedding (this thread: a=i, j=k)
    {
      const float* hj = &h_s[cur][i*16];
      float hw = 0.0f;
      #pragma unroll
      for (int m = 0; m < 16; ++m) hw = fmaf(hj[m], wm[16+m], hw);
      hW_s[i*16+k] = hw;

      float rx = pos_s[i*2+0] - pos_s[k*2+0];
      float ry = pos_s[i*2+1] - pos_s[k*2+1];
      float rv[16];
      #pragma unroll
      for (int m = 0; m < 16; ++m)
        rv[m] = fmaxf(fmaf(ry, sW_pr[16+m], fmaf(rx, sW_pr[m], sb_pr[m])), 0.0f);
      float* rp = &re_s[i*324 + k*20];
      *(float4*)(rp+0)  = make_float4(rv[0],rv[1],rv[2],rv[3]);
      *(float4*)(rp+4)  = make_float4(rv[4],rv[5],rv[6],rv[7]);
      *(float4*)(rp+8)  = make_float4(rv[8],rv[9],rv[10],rv[11]);
      *(float4*)(rp+12) = make_float4(rv[12],rv[13],rv[14],rv[15]);
    }
    __syncthreads(); // C
    // phase 4: masked max-pool over neighbors j
    {
      float pooled = -1e30f;
      const float* rb = &re_s[i*324];
      #pragma unroll
      for (int j = 0; j < 16; ++j) {
        const float* rp = rb + j*20;
        float4 r0 = ld4(rp), r1 = ld4(rp+4), r2 = ld4(rp+8), r3 = ld4(rp+12);
        float acc = bmlp + hW_s[j*16+k];
        acc += r0.x*wm[0]  + r0.y*wm[1]  + r0.z*wm[2]  + r0.w*wm[3]
             + r1.x*wm[4]  + r1.y*wm[5]  + r1.z*wm[6]  + r1.w*wm[7]
             + r2.x*wm[8]  + r2.y*wm[9]  + r2.z*wm[10] + r2.w*wm[11]
             + r3.x*wm[12] + r3.y*wm[13] + r3.z*wm[14] + r3.w*wm[15];
        float feat = fmaxf(acc, 0.0f);
        if ((mbits >> j) & 1u) pooled = fmaxf(pooled, feat);
      }
      ctx_s[i*16+k] = has ? pooled : 0.0f;
    }
    __syncthreads(); // D
    // phase 5+6: o4 = (h+ctx)@out_W + b; mu/std/pred; write outputs; advance pos
    {
      float o4v = 0.0f;
      if (k < 4) {
        const float* hp = &h_s[cur][i*16];
        const float* cx = &ctx_s[i*16];
        float acc = sb_o[k];
        #pragma unroll
        for (int m = 0; m < 16; ++m) acc = fmaf(hp[m]+cx[m], sW_o[m*4+k], acc);
        o4v = acc;
      }
      float sc = __shfl_down(o4v, 2, 64);   // lane k<2 grabs o4[2+k]
      if (k < 2) {
        float mu = o4v;
        float scale = fminf(fmaxf(sc, -9.0f), 4.0f);
        float sd = __expf(scale);
        float nz = noise[(t*B_ + bi)*2 + k];
        float pr = fmaf(sd, nz, mu);
        int o = (t*B_ + bi)*2 + k;
        out[o]          = pr;
        out[MU_OFF + o] = mu;
        out[SD_OFF + o] = sd;
        pos_s[i*2+k] += pr;
        prev_s[i*2+k] = pr;
      }
    }
    __syncthreads(); // E
  }
}

extern "C" void kernel_launch(void* const* d_in, const int* in_sizes, int n_in,
                              void* d_out, int out_size, void* d_ws, size_t ws_size,
                              hipStream_t stream) {
  (void)in_sizes; (void)n_in; (void)d_ws; (void)ws_size; (void)out_size;
  traj_ar_kernel<<<dim3(S_), dim3(256), 0, stream>>>(
      (const float*)d_in[0],  (const float*)d_in[1],  (const int*)d_in[2],   (const float*)d_in[3],
      (const float*)d_in[4],  (const float*)d_in[5],  (const float*)d_in[6], (const float*)d_in[7],
      (const float*)d_in[8],  (const float*)d_in[9],  (const float*)d_in[10],(const float*)d_in[11],
      (const float*)d_in[12], (const float*)d_in[13], (const float*)d_in[14],(const float*)d_in[15],
      (const float*)d_in[16], (const float*)d_in[17], (const float*)d_in[18],(const float*)d_in[19],
      (float*)d_out);
}

// Round 6
// 246.798 us; speedup vs baseline: 2.2480x; 1.2869x over previous
//
#include <hip/hip_runtime.h>

#define S_    2048
#define N_    16
#define OBS_  8
#define PRED_ 12
#define B_    (S_*N_)

typedef __attribute__((ext_vector_type(8))) short short8;
typedef __attribute__((ext_vector_type(4))) float floatx4;
typedef __attribute__((ext_vector_type(4))) unsigned uintx4;
typedef unsigned short ushort_t;

__device__ __forceinline__ float4 ld4(const float* p) { return *(const float4*)p; }
__device__ __forceinline__ float sigmf(float x) { return __builtin_amdgcn_rcpf(1.0f + __expf(-x)); }
__device__ __forceinline__ float tanhx(float x) { return fmaf(-2.0f, __builtin_amdgcn_rcpf(1.0f + __expf(2.0f*x)), 1.0f); }
// f32 -> bf16 RNE, pure bit ops
__device__ __forceinline__ unsigned f2bfu(float f) {
  unsigned u = __builtin_bit_cast(unsigned, f);
  return (u + 0x7FFFu + ((u >> 16) & 1u)) >> 16;
}
__device__ __forceinline__ unsigned pack2bf(float lo, float hi) {
  return f2bfu(lo) | (f2bfu(hi) << 16);
}

__device__ __forceinline__ float dot16w(const float* w, const float4 x0, const float4 x1,
                                        const float4 x2, const float4 x3) {
  float4 w0 = ld4(w); float4 w1 = ld4(w+4); float4 w2 = ld4(w+8); float4 w3 = ld4(w+12);
  float a = x0.x*w0.x + x0.y*w0.y + x0.z*w0.z + x0.w*w0.w;
  float b = x1.x*w1.x + x1.y*w1.y + x1.z*w1.z + x1.w*w1.w;
  float c = x2.x*w2.x + x2.y*w2.y + x2.z*w2.z + x2.w*w2.w;
  float d = x3.x*w3.x + x3.y*w3.y + x3.z*w3.z + x3.w*w3.w;
  return (a+b)+(c+d);
}

// one scene per block; thread (i = agent, k = hidden unit), 256 threads.
// NOTE: keep the R1/R5 barrier structure (5/decoder step). Removing barriers and
// merging phases (R2-R4) made the scheduler extend live ranges across phases,
// demoting arrays to scratch: 700-900 MB HBM spill traffic (scratch working set
// > 4 MB/XCD L2). Barriers are scheduling fences keeping live ranges short.
// R6: phase 4 via MFMA inside the intact skeleton (R4 proved MFMA was not the
// spill cause - phase merging was).
extern "C" __global__ __launch_bounds__(256, 4) void traj_ar_kernel(
    const float* __restrict__ traj_rel, const float* __restrict__ obs_pos,
    const int*  __restrict__ nei,       const float* __restrict__ noise,
    const float* __restrict__ eeW, const float* __restrict__ eeb,
    const float* __restrict__ eWi, const float* __restrict__ eWh, const float* __restrict__ eb,
    const float* __restrict__ diW, const float* __restrict__ dib,
    const float* __restrict__ dWi, const float* __restrict__ dWh, const float* __restrict__ db,
    const float* __restrict__ prW, const float* __restrict__ prb,
    const float* __restrict__ mW,  const float* __restrict__ mb,
    const float* __restrict__ oW,  const float* __restrict__ ob,
    float* __restrict__ out)
{
  // weights: LSTM mats transposed, row stride 20 floats (80B: b128-aligned, 2-way bank alias = free)
  __shared__ __align__(16) float sW_ee[32];
  __shared__ __align__(16) float sb_ee[16];
  __shared__ __align__(16) float sW_eiT[64*20];
  __shared__ __align__(16) float sW_ehT[64*20];
  __shared__ __align__(16) float sb_e[64];
  __shared__ __align__(16) float sW_diT[16*20];   // 18 rows used of stride 20
  __shared__ __align__(16) float sb_di[16];
  __shared__ __align__(16) float sW_dWiT[64*20];
  __shared__ __align__(16) float sW_dWhT[64*20];
  __shared__ __align__(16) float sb_d[64];
  __shared__ __align__(16) float sW_pr[32];
  __shared__ __align__(16) float sb_pr[16];
  __shared__ __align__(16) float sW_o[64];
  __shared__ __align__(16) float sb_o[4];
  // state
  __shared__ __align__(16) float h_s[2][256];
  __shared__ __align__(16) float e_s[256];
  __shared__ __align__(16) float ctx_s[256];
  // pool inputs in bf16 for MFMA. re_s[i][j][m]: j-stride 24 ushorts (48B:
  // b128-aligned, store start banks 12k mod 32 cover 8 bank-quads, 2-way = free),
  // i-stride 392 ushorts (784B, 16B-aligned).
  __shared__ __align__(16) ushort_t re_s[16*392];
  __shared__ __align__(16) ushort_t hb_s[16*24];
  __shared__ __align__(16) float pos_s[32];
  __shared__ __align__(16) float prev_s[32];
  __shared__            unsigned sm_s[16];   // neighbor mask bits per agent

  const int tid = threadIdx.x;
  const int s = blockIdx.x;
  const int i = tid >> 4;
  const int k = tid & 15;
  const int bi = s*N_ + i;

  // ---- stage weights into LDS ----
  if (tid < 32) sW_ee[tid] = eeW[tid];
  if (tid < 16) sb_ee[tid] = eeb[tid];
  for (int idx = tid; idx < 1024; idx += 256) {
    int m = idx >> 6, c = idx & 63;
    sW_eiT[c*20+m] = eWi[idx];
    sW_ehT[c*20+m] = eWh[idx];
    sW_dWiT[c*20+m] = dWi[idx];
    sW_dWhT[c*20+m] = dWh[idx];
  }
  if (tid < 64) sb_e[tid] = eb[tid];
  for (int idx = tid; idx < 288; idx += 256) { int m = idx >> 4, c = idx & 15; sW_diT[c*20+m] = diW[idx]; }
  if (tid < 16) sb_di[tid] = dib[tid];
  if (tid < 64) sb_d[tid] = db[tid];
  if (tid < 32) sW_pr[tid] = prW[tid];
  if (tid < 16) sb_pr[tid] = prb[tid];
  if (tid < 64) sW_o[tid] = oW[tid];
  if (tid < 4)  sb_o[tid] = ob[tid];

  h_s[0][tid] = 0.0f;
  ctx_s[tid] = 0.0f;
  if (k < 2) {
    prev_s[i*2+k] = traj_rel[((OBS_-1)*B_ + bi)*2 + k];  // out init = traj_rel[OBS-1]
    pos_s[i*2+k]  = obs_pos[((OBS_-1)*B_ + bi)*2 + k];   // pos init = obs_traj_pos[-1]
  }

  // pool-MLP B-fragment (32x16 bf16 weights) in 4 VGPRs + bias; replaces R5's wm[32]
  const int lq = (tid & 63) >> 4;       // quad within wave
  const int lc = tid & 15;              // col within wave (== k)
  uintx4 bw;
  #pragma unroll
  for (int p = 0; p < 4; ++p)
    bw[p] = pack2bf(mW[(8*lq + 2*p)*16 + lc], mW[(8*lq + 2*p + 1)*16 + lc]);
  const short8 bfrag = __builtin_bit_cast(short8, bw);
  floatx4 cinit;
  { float bm = mb[lc]; cinit[0]=bm; cinit[1]=bm; cinit[2]=bm; cinit[3]=bm; }

  // time-invariant neighbor mask -> per-agent bitmask in LDS (read by pool phase)
  unsigned long long bal = __ballot(nei[bi*N_ + k] > 0);
  if (k == 0) sm_s[i] = (unsigned)((bal >> (16*(i & 3))) & 0xFFFFull);

  __syncthreads();

  // ---- encoder: 8 LSTM steps ----
  int cur = 0;
  float c_reg = 0.0f;
  const float2* xr2 = (const float2*)traj_rel;
  for (int t = 0; t < OBS_; ++t) {
    float2 x = xr2[t*B_ + bi];
    float em[16];
    #pragma unroll
    for (int m = 0; m < 16; ++m)
      em[m] = fmaxf(fmaf(x.y, sW_ee[16+m], fmaf(x.x, sW_ee[m], sb_ee[m])), 0.0f);
    float4 e0 = make_float4(em[0],em[1],em[2],em[3]);
    float4 e1 = make_float4(em[4],em[5],em[6],em[7]);
    float4 e2 = make_float4(em[8],em[9],em[10],em[11]);
    float4 e3 = make_float4(em[12],em[13],em[14],em[15]);
    const float* hp = &h_s[cur][i*16];
    float4 h0 = ld4(hp), h1 = ld4(hp+4), h2 = ld4(hp+8), h3 = ld4(hp+12);
    float g0 = sb_e[k]    + dot16w(&sW_eiT[(k)*20],    e0,e1,e2,e3) + dot16w(&sW_ehT[(k)*20],    h0,h1,h2,h3);
    float g1 = sb_e[k+16] + dot16w(&sW_eiT[(k+16)*20], e0,e1,e2,e3) + dot16w(&sW_ehT[(k+16)*20], h0,h1,h2,h3);
    float g2 = sb_e[k+32] + dot16w(&sW_eiT[(k+32)*20], e0,e1,e2,e3) + dot16w(&sW_ehT[(k+32)*20], h0,h1,h2,h3);
    float g3 = sb_e[k+48] + dot16w(&sW_eiT[(k+48)*20], e0,e1,e2,e3) + dot16w(&sW_ehT[(k+48)*20], h0,h1,h2,h3);
    float ig = sigmf(g0), fg = sigmf(g1), gv = tanhx(g2), og = sigmf(g3);
    c_reg = fg*c_reg + ig*gv;
    float nh = og * tanhx(c_reg);
    h_s[cur^1][i*16+k] = nh;   // write other buffer: no read/write race
    __syncthreads();
    cur ^= 1;
  }

  // ---- decoder: 12 autoregressive steps ----
  c_reg = 0.0f;                       // decoder c starts at zero
  const int MU_OFF = PRED_*B_*2;
  const int SD_OFF = 2*PRED_*B_*2;
  const int w = tid >> 6;
  for (int t = 0; t < PRED_; ++t) {
    // phase 1: e = relu([ctx, prev] @ dec_in_W + b)
    {
      const float* cx = &ctx_s[i*16];
      float4 c0 = ld4(cx), c1 = ld4(cx+4), c2 = ld4(cx+8), c3 = ld4(cx+12);
      float p0 = prev_s[i*2+0], p1 = prev_s[i*2+1];
      const float* wd = &sW_diT[k*20];
      float acc = sb_di[k] + dot16w(wd, c0,c1,c2,c3) + p0*wd[16] + p1*wd[17];
      e_s[i*16+k] = fmaxf(acc, 0.0f);
    }
    __syncthreads(); // A
    // phase 2: LSTM cell; also write bf16 h copy for the pool matmul
    {
      const float* ep = &e_s[i*16];
      float4 e0 = ld4(ep), e1 = ld4(ep+4), e2 = ld4(ep+8), e3 = ld4(ep+12);
      const float* hp = &h_s[cur][i*16];
      float4 h0 = ld4(hp), h1 = ld4(hp+4), h2 = ld4(hp+8), h3 = ld4(hp+12);
      float g0 = sb_d[k]    + dot16w(&sW_dWiT[(k)*20],    e0,e1,e2,e3) + dot16w(&sW_dWhT[(k)*20],    h0,h1,h2,h3);
      float g1 = sb_d[k+16] + dot16w(&sW_dWiT[(k+16)*20], e0,e1,e2,e3) + dot16w(&sW_dWhT[(k+16)*20], h0,h1,h2,h3);
      float g2 = sb_d[k+32] + dot16w(&sW_dWiT[(k+32)*20], e0,e1,e2,e3) + dot16w(&sW_dWhT[(k+32)*20], h0,h1,h2,h3);
      float g3 = sb_d[k+48] + dot16w(&sW_dWiT[(k+48)*20], e0,e1,e2,e3) + dot16w(&sW_dWhT[(k+48)*20], h0,h1,h2,h3);
      float ig = sigmf(g0), fg = sigmf(g1), gv = tanhx(g2), og = sigmf(g3);
      c_reg = fg*c_reg + ig*gv;
      float nh = og * tanhx(c_reg);
      h_s[cur^1][i*16+k] = nh;
      hb_s[i*24 + k] = (ushort_t)f2bfu(nh);
    }
    __syncthreads(); // B
    cur ^= 1;
    // phase 3: re[i][j=k][:] = relu(rel @ prW + b), bf16 packed pairs -> two b128 stores
    {
      float rx = pos_s[i*2+0] - pos_s[k*2+0];
      float ry = pos_s[i*2+1] - pos_s[k*2+1];
      uintx4 v0, v1;
      #pragma unroll
      for (int m = 0; m < 4; ++m) {
        float a0 = fmaxf(fmaf(ry, sW_pr[16+2*m], fmaf(rx, sW_pr[2*m],   sb_pr[2*m])),   0.0f);
        float a1 = fmaxf(fmaf(ry, sW_pr[17+2*m], fmaf(rx, sW_pr[2*m+1], sb_pr[2*m+1])), 0.0f);
        float b0 = fmaxf(fmaf(ry, sW_pr[24+2*m], fmaf(rx, sW_pr[8+2*m], sb_pr[8+2*m])), 0.0f);
        float b1 = fmaxf(fmaf(ry, sW_pr[25+2*m], fmaf(rx, sW_pr[9+2*m], sb_pr[9+2*m])), 0.0f);
        v0[m] = pack2bf(a0, a1);
        v1[m] = pack2bf(b0, b1);
      }
      uintx4* rp = (uintx4*)&re_s[i*392 + k*24];
      rp[0] = v0;
      rp[1] = v1;
    }
    __syncthreads(); // C
    // phase 4: masked max-pool via MFMA. Tile = agent it of this wave;
    // A[j][0:16]=re[it][j][:], A[j][16:32]=h[j][:]; D[j][k] -> masked max over j.
    {
      const ushort_t* hbp = &hb_s[lc*24 + (lq-2)*8];
      #pragma unroll
      for (int tt = 0; tt < 4; ++tt) {
        const int it = 4*w + tt;
        const ushort_t* rep = &re_s[it*392 + lc*24 + lq*8];
        const ushort_t* ap = (lq < 2) ? rep : hbp;
        short8 a = *(const short8*)ap;
        floatx4 d = __builtin_amdgcn_mfma_f32_16x16x32_bf16(a, bfrag, cinit, 0, 0, 0);
        const unsigned mi = sm_s[it];
        float pm = -1e30f;
        #pragma unroll
        for (int r = 0; r < 4; ++r) {
          float feat = fmaxf(d[r], 0.0f);            // row j = lq*4+r, col k = lc
          bool on = (mi >> (lq*4 + r)) & 1u;
          pm = on ? fmaxf(pm, feat) : pm;
        }
        pm = fmaxf(pm, __shfl_xor(pm, 16, 64));
        pm = fmaxf(pm, __shfl_xor(pm, 32, 64));
        if (lq == tt) ctx_s[it*16 + lc] = (mi != 0u) ? pm : 0.0f;  // quad tt owns tile tt
      }
    }
    __syncthreads(); // D
    // phase 5: o4 = (h+ctx)@out_W + b; mu/std/pred; write outputs; advance pos
    {
      float o4v = 0.0f;
      if (k < 4) {
        const float* hp = &h_s[cur][i*16];
        const float* cx = &ctx_s[i*16];
        float acc = sb_o[k];
        #pragma unroll
        for (int m = 0; m < 16; ++m) acc = fmaf(hp[m]+cx[m], sW_o[m*4+k], acc);
        o4v = acc;
      }
      float sc = __shfl_down(o4v, 2, 64);   // lane k<2 grabs o4[2+k]
      if (k < 2) {
        float mu = o4v;
        float scale = fminf(fmaxf(sc, -9.0f), 4.0f);
        float sd = __expf(scale);
        float nz = noise[(t*B_ + bi)*2 + k];
        float pr = fmaf(sd, nz, mu);
        int o = (t*B_ + bi)*2 + k;
        out[o]          = pr;
        out[MU_OFF + o] = mu;
        out[SD_OFF + o] = sd;
        pos_s[i*2+k] += pr;
        prev_s[i*2+k] = pr;
      }
    }
    __syncthreads(); // E
  }
}

extern "C" void kernel_launch(void* const* d_in, const int* in_sizes, int n_in,
                              void* d_out, int out_size, void* d_ws, size_t ws_size,
                              hipStream_t stream) {
  (void)in_sizes; (void)n_in; (void)d_ws; (void)ws_size; (void)out_size;
  traj_ar_kernel<<<dim3(S_), dim3(256), 0, stream>>>(
      (const float*)d_in[0],  (const float*)d_in[1],  (const int*)d_in[2],   (const float*)d_in[3],
      (const float*)d_in[4],  (const float*)d_in[5],  (const float*)d_in[6], (const float*)d_in[7],
      (const float*)d_in[8],  (const float*)d_in[9],  (const float*)d_in[10],(const float*)d_in[11],
      (const float*)d_in[12], (const float*)d_in[13], (const float*)d_in[14],(const float*)d_in[15],
      (const float*)d_in[16], (const float*)d_in[17], (const float*)d_in[18],(const float*)d_in[19],
      (float*)d_out);
}

// Round 7
// 215.351 us; speedup vs baseline: 2.5762x; 1.1460x over previous
//
#include <hip/hip_runtime.h>

#define S_    2048
#define N_    16
#define OBS_  8
#define PRED_ 12
#define B_    (S_*N_)

typedef __attribute__((ext_vector_type(8))) short short8;
typedef __attribute__((ext_vector_type(4))) float floatx4;
typedef __attribute__((ext_vector_type(4))) unsigned uintx4;
typedef unsigned short ushort_t;

__device__ __forceinline__ float4 ld4(const float* p) { return *(const float4*)p; }
__device__ __forceinline__ float sigmf(float x) { return __builtin_amdgcn_rcpf(1.0f + __expf(-x)); }
__device__ __forceinline__ float tanhx(float x) { return fmaf(-2.0f, __builtin_amdgcn_rcpf(1.0f + __expf(2.0f*x)), 1.0f); }
// f32 -> bf16 RNE, pure bit ops
__device__ __forceinline__ unsigned f2bfu(float f) {
  unsigned u = __builtin_bit_cast(unsigned, f);
  return (u + 0x7FFFu + ((u >> 16) & 1u)) >> 16;
}
__device__ __forceinline__ unsigned pack2bf(float lo, float hi) {
  return f2bfu(lo) | (f2bfu(hi) << 16);
}

__device__ __forceinline__ float dot16w(const float* w, const float4 x0, const float4 x1,
                                        const float4 x2, const float4 x3) {
  float4 w0 = ld4(w); float4 w1 = ld4(w+4); float4 w2 = ld4(w+8); float4 w3 = ld4(w+12);
  float a = x0.x*w0.x + x0.y*w0.y + x0.z*w0.z + x0.w*w0.w;
  float b = x1.x*w1.x + x1.y*w1.y + x1.z*w1.z + x1.w*w1.w;
  float c = x2.x*w2.x + x2.y*w2.y + x2.z*w2.z + x2.w*w2.w;
  float d = x3.x*w3.x + x3.y*w3.y + x3.z*w3.z + x3.w*w3.w;
  return (a+b)+(c+d);
}

// one scene per block; thread (i = agent, k = hidden unit), 256 threads.
// SKELETON RULE (R2-R5 evidence): keep every barrier; change only phase bodies.
// Merging phases / removing barriers extends live ranges -> scratch spills ->
// 700-900 MB HBM traffic. Barriers are scheduling fences.
// R7: LSTM gates via MFMA. D[unit][agent] per gate type; A-frag = weights
// (registers, constant), B-frag = [e|h] bf16 from LDS (1 ds_read_b128),
// bias in C operand. c-state = 4-unit register fragment per lane (all waves
// redundantly compute all agents; owner wave writes h back).
extern "C" __global__ __launch_bounds__(256, 4) void traj_ar_kernel(
    const float* __restrict__ traj_rel, const float* __restrict__ obs_pos,
    const int*  __restrict__ nei,       const float* __restrict__ noise,
    const float* __restrict__ eeW, const float* __restrict__ eeb,
    const float* __restrict__ eWi, const float* __restrict__ eWh, const float* __restrict__ eb,
    const float* __restrict__ diW, const float* __restrict__ dib,
    const float* __restrict__ dWi, const float* __restrict__ dWh, const float* __restrict__ db,
    const float* __restrict__ prW, const float* __restrict__ prb,
    const float* __restrict__ mW,  const float* __restrict__ mb,
    const float* __restrict__ oW,  const float* __restrict__ ob,
    float* __restrict__ out)
{
  // dec-in weights transposed, row stride 20 floats (80B, 2-way bank alias = free)
  __shared__ __align__(16) float sW_diT[16*20];   // 18 rows used of stride 20
  __shared__ __align__(16) float sb_di[16];
  __shared__ __align__(16) float sW_pr[32];
  __shared__ __align__(16) float sb_pr[16];
  __shared__ __align__(16) float sW_o[64];
  __shared__ __align__(16) float sb_o[4];
  // state
  __shared__ __align__(16) float h_s[256];        // f32 h, phase-5 input
  __shared__ __align__(16) float ctx_s[256];
  // bf16 activations, [agent][unit] stride 24 ushorts (48B: b128-aligned,
  // 12-word row starts cover 8 bank-quads; b128 reads land at the 8 words/bank floor)
  __shared__ __align__(16) ushort_t e_bf[16*24];
  __shared__ __align__(16) ushort_t hb_s[16*24];
  // pool embeddings bf16: [i][j] j-stride 24 ushorts, i-stride 392 (784B, 16B-aligned)
  __shared__ __align__(16) ushort_t re_s[16*392];
  __shared__ __align__(16) float pos_s[32];
  __shared__ __align__(16) float prev_s[32];
  __shared__            unsigned sm_s[16];   // neighbor mask bits per agent

  const int tid = threadIdx.x;
  const int s = blockIdx.x;
  const int i = tid >> 4;
  const int k = tid & 15;
  const int bi = s*N_ + i;
  const int lq = (tid & 63) >> 4;       // quad within wave
  const int lc = tid & 15;              // col within wave (== k)
  const int w  = tid >> 6;              // wave index; wave w owns agents 4w..4w+3

  // ---- stage small weights into LDS ----
  for (int idx = tid; idx < 288; idx += 256) { int m = idx >> 4, c = idx & 15; sW_diT[c*20+m] = diW[idx]; }
  if (tid < 16) sb_di[tid] = dib[tid];
  if (tid < 32) sW_pr[tid] = prW[tid];
  if (tid < 16) sb_pr[tid] = prb[tid];
  if (tid < 64) sW_o[tid] = oW[tid];
  if (tid < 4)  sb_o[tid] = ob[tid];
  if (tid < 192) ((unsigned*)hb_s)[tid] = 0;   // h0 = 0 for first encoder step

  ctx_s[tid] = 0.0f;
  if (k < 2) {
    prev_s[i*2+k] = traj_rel[((OBS_-1)*B_ + bi)*2 + k];  // out init = traj_rel[OBS-1]
    pos_s[i*2+k]  = obs_pos[((OBS_-1)*B_ + bi)*2 + k];   // pos init = obs_traj_pos[-1]
  }

  // pool-MLP B-fragment (32x16 bf16 weights) + bias
  short8 bfrag;
  {
    uintx4 bw;
    #pragma unroll
    for (int p = 0; p < 4; ++p)
      bw[p] = pack2bf(mW[(8*lq + 2*p)*16 + lc], mW[(8*lq + 2*p + 1)*16 + lc]);
    bfrag = __builtin_bit_cast(short8, bw);
  }
  floatx4 cinit;
  { float bm = mb[lc]; cinit[0]=bm; cinit[1]=bm; cinit[2]=bm; cinit[3]=bm; }

  // encoder embed weights per thread (unit k)
  const float w0k = eeW[k], w1k = eeW[16+k], bek = eeb[k];

  // encoder gate A-fragments (weights; constant all steps) + bias C operands.
  // A_gt[m=unit=lc][kk=lq*8+j]: kk<16 -> Wi[kk][gt*16+m], else Wh[kk-16][...]
  short8 gA0, gA1, gA2, gA3; floatx4 gC0, gC1, gC2, gC3;
  {
    const int row0 = (lq & 1) * 8;
    const float* gsrc = (lq & 2) ? eWh : eWi;
    #pragma unroll
    for (int gt = 0; gt < 4; ++gt) {
      uintx4 aw;
      #pragma unroll
      for (int p = 0; p < 4; ++p)
        aw[p] = pack2bf(gsrc[(row0+2*p)*64 + gt*16 + lc], gsrc[(row0+2*p+1)*64 + gt*16 + lc]);
      short8 af = __builtin_bit_cast(short8, aw);
      floatx4 cf;
      #pragma unroll
      for (int r = 0; r < 4; ++r) cf[r] = eb[gt*16 + lq*4 + r];
      if (gt==0) { gA0=af; gC0=cf; } else if (gt==1) { gA1=af; gC1=cf; }
      else if (gt==2) { gA2=af; gC2=cf; } else { gA3=af; gC3=cf; }
    }
  }

  // time-invariant neighbor mask -> per-agent bitmask in LDS
  unsigned long long bal = __ballot(nei[bi*N_ + k] > 0);
  if (k == 0) sm_s[i] = (unsigned)((bal >> (16*(i & 3))) & 0xFFFFull);

  __syncthreads();

  // ---- encoder: 8 LSTM steps, 2 barriers/step ----
  floatx4 cfrag; cfrag[0]=0.f; cfrag[1]=0.f; cfrag[2]=0.f; cfrag[3]=0.f;
  const float2* xr2 = (const float2*)traj_rel;
  const bool owner = ((lc >> 2) == w);
  for (int t = 0; t < OBS_; ++t) {
    // P1e: e[i][k] = relu(x @ eeW + b), bf16 to LDS
    {
      float2 x = xr2[t*B_ + bi];
      float e = fmaxf(fmaf(x.y, w1k, fmaf(x.x, w0k, bek)), 0.0f);
      e_bf[i*24 + k] = (ushort_t)f2bfu(e);
    }
    __syncthreads(); // A: e_bf ready (and prev hb_s write drained)
    // P2e: gates via 4 MFMA, elementwise, h
    float hv0, hv1, hv2, hv3;
    {
      const ushort_t* bp = (lq < 2) ? &e_bf[lc*24 + (lq&1)*8] : &hb_s[lc*24 + (lq&1)*8];
      short8 bfr = *(const short8*)bp;
      floatx4 gI = __builtin_amdgcn_mfma_f32_16x16x32_bf16(gA0, bfr, gC0, 0, 0, 0);
      floatx4 gF = __builtin_amdgcn_mfma_f32_16x16x32_bf16(gA1, bfr, gC1, 0, 0, 0);
      floatx4 gG = __builtin_amdgcn_mfma_f32_16x16x32_bf16(gA2, bfr, gC2, 0, 0, 0);
      floatx4 gO = __builtin_amdgcn_mfma_f32_16x16x32_bf16(gA3, bfr, gC3, 0, 0, 0);
      float hv[4];
      #pragma unroll
      for (int r = 0; r < 4; ++r) {
        float ig = sigmf(gI[r]), fg = sigmf(gF[r]), gv = tanhx(gG[r]), og = sigmf(gO[r]);
        cfrag[r] = fg*cfrag[r] + ig*gv;
        hv[r] = og * tanhx(cfrag[r]);
      }
      hv0=hv[0]; hv1=hv[1]; hv2=hv[2]; hv3=hv[3];
    }
    __syncthreads(); // B: all hb_s reads done before owner overwrites
    if (owner) {
      uint2 hp2; hp2.x = pack2bf(hv0, hv1); hp2.y = pack2bf(hv2, hv3);
      *(uint2*)&hb_s[lc*24 + lq*4] = hp2;
    }
  }

  // decoder gate A-fragments + biases (loaded after encoder: separate live ranges)
  short8 dA0, dA1, dA2, dA3; floatx4 dC0, dC1, dC2, dC3;
  {
    const int row0 = (lq & 1) * 8;
    const float* gsrc = (lq & 2) ? dWh : dWi;
    #pragma unroll
    for (int gt = 0; gt < 4; ++gt) {
      uintx4 aw;
      #pragma unroll
      for (int p = 0; p < 4; ++p)
        aw[p] = pack2bf(gsrc[(row0+2*p)*64 + gt*16 + lc], gsrc[(row0+2*p+1)*64 + gt*16 + lc]);
      short8 af = __builtin_bit_cast(short8, aw);
      floatx4 cf;
      #pragma unroll
      for (int r = 0; r < 4; ++r) cf[r] = db[gt*16 + lq*4 + r];
      if (gt==0) { dA0=af; dC0=cf; } else if (gt==1) { dA1=af; dC1=cf; }
      else if (gt==2) { dA2=af; dC2=cf; } else { dA3=af; dC3=cf; }
    }
  }

  // ---- decoder: 12 autoregressive steps, 5 barriers/step ----
  cfrag[0]=0.f; cfrag[1]=0.f; cfrag[2]=0.f; cfrag[3]=0.f;  // decoder c starts at 0
  const int MU_OFF = PRED_*B_*2;
  const int SD_OFF = 2*PRED_*B_*2;
  for (int t = 0; t < PRED_; ++t) {
    // phase 1: e = relu([ctx, prev] @ dec_in_W + b), bf16 to LDS
    {
      const float* cx = &ctx_s[i*16];
      float4 c0 = ld4(cx), c1 = ld4(cx+4), c2 = ld4(cx+8), c3 = ld4(cx+12);
      float p0 = prev_s[i*2+0], p1 = prev_s[i*2+1];
      const float* wd = &sW_diT[k*20];
      float acc = sb_di[k] + dot16w(wd, c0,c1,c2,c3) + p0*wd[16] + p1*wd[17];
      e_bf[i*24 + k] = (ushort_t)f2bfu(fmaxf(acc, 0.0f));
    }
    __syncthreads(); // A
    // phase 2: gates via 4 MFMA (h input = hb_s from prev step), elementwise
    float hv0, hv1, hv2, hv3;
    {
      const ushort_t* bp = (lq < 2) ? &e_bf[lc*24 + (lq&1)*8] : &hb_s[lc*24 + (lq&1)*8];
      short8 bfr = *(const short8*)bp;
      floatx4 gI = __builtin_amdgcn_mfma_f32_16x16x32_bf16(dA0, bfr, dC0, 0, 0, 0);
      floatx4 gF = __builtin_amdgcn_mfma_f32_16x16x32_bf16(dA1, bfr, dC1, 0, 0, 0);
      floatx4 gG = __builtin_amdgcn_mfma_f32_16x16x32_bf16(dA2, bfr, dC2, 0, 0, 0);
      floatx4 gO = __builtin_amdgcn_mfma_f32_16x16x32_bf16(dA3, bfr, dC3, 0, 0, 0);
      float hv[4];
      #pragma unroll
      for (int r = 0; r < 4; ++r) {
        float ig = sigmf(gI[r]), fg = sigmf(gF[r]), gv = tanhx(gG[r]), og = sigmf(gO[r]);
        cfrag[r] = fg*cfrag[r] + ig*gv;
        hv[r] = og * tanhx(cfrag[r]);
      }
      hv0=hv[0]; hv1=hv[1]; hv2=hv[2]; hv3=hv[3];
    }
    __syncthreads(); // B: all hb_s reads done before owner overwrites
    if (owner) {
      *(float4*)&h_s[lc*16 + lq*4] = make_float4(hv0, hv1, hv2, hv3);
      uint2 hp2; hp2.x = pack2bf(hv0, hv1); hp2.y = pack2bf(hv2, hv3);
      *(uint2*)&hb_s[lc*24 + lq*4] = hp2;
    }
    // phase 3: re[i][j=k][:] = relu(rel @ prW + b), bf16 packed -> two b128 stores
    {
      float rx = pos_s[i*2+0] - pos_s[k*2+0];
      float ry = pos_s[i*2+1] - pos_s[k*2+1];
      uintx4 v0, v1;
      #pragma unroll
      for (int m = 0; m < 4; ++m) {
        float a0 = fmaxf(fmaf(ry, sW_pr[16+2*m], fmaf(rx, sW_pr[2*m],   sb_pr[2*m])),   0.0f);
        float a1 = fmaxf(fmaf(ry, sW_pr[17+2*m], fmaf(rx, sW_pr[2*m+1], sb_pr[2*m+1])), 0.0f);
        float b0 = fmaxf(fmaf(ry, sW_pr[24+2*m], fmaf(rx, sW_pr[8+2*m], sb_pr[8+2*m])), 0.0f);
        float b1 = fmaxf(fmaf(ry, sW_pr[25+2*m], fmaf(rx, sW_pr[9+2*m], sb_pr[9+2*m])), 0.0f);
        v0[m] = pack2bf(a0, a1);
        v1[m] = pack2bf(b0, b1);
      }
      uintx4* rp = (uintx4*)&re_s[i*392 + k*24];
      rp[0] = v0;
      rp[1] = v1;
    }
    __syncthreads(); // C
    // phase 4: masked max-pool via MFMA. Tile = agent it of this wave;
    // A[j][0:16]=re[it][j][:], A[j][16:32]=h[j][:]; D[j][k] -> masked max over j.
    {
      const ushort_t* hbp = &hb_s[lc*24 + (lq-2)*8];
      #pragma unroll
      for (int tt = 0; tt < 4; ++tt) {
        const int it = 4*w + tt;
        const ushort_t* rep = &re_s[it*392 + lc*24 + lq*8];
        const ushort_t* ap = (lq < 2) ? rep : hbp;
        short8 a = *(const short8*)ap;
        floatx4 d = __builtin_amdgcn_mfma_f32_16x16x32_bf16(a, bfrag, cinit, 0, 0, 0);
        const unsigned mi = sm_s[it];
        float pm = -1e30f;
        #pragma unroll
        for (int r = 0; r < 4; ++r) {
          float feat = fmaxf(d[r], 0.0f);            // row j = lq*4+r, col k = lc
          bool on = (mi >> (lq*4 + r)) & 1u;
          pm = on ? fmaxf(pm, feat) : pm;
        }
        pm = fmaxf(pm, __shfl_xor(pm, 16, 64));
        pm = fmaxf(pm, __shfl_xor(pm, 32, 64));
        if (lq == tt) ctx_s[it*16 + lc] = (mi != 0u) ? pm : 0.0f;  // quad tt owns tile tt
      }
    }
    __syncthreads(); // D
    // phase 5: o4 = (h+ctx)@out_W + b; mu/std/pred; write outputs; advance pos
    {
      float o4v = 0.0f;
      if (k < 4) {
        const float* hp = &h_s[i*16];
        const float* cx = &ctx_s[i*16];
        float acc = sb_o[k];
        #pragma unroll
        for (int m = 0; m < 16; ++m) acc = fmaf(hp[m]+cx[m], sW_o[m*4+k], acc);
        o4v = acc;
      }
      float sc = __shfl_down(o4v, 2, 64);   // lane k<2 grabs o4[2+k]
      if (k < 2) {
        float mu = o4v;
        float scale = fminf(fmaxf(sc, -9.0f), 4.0f);
        float sd = __expf(scale);
        float nz = noise[(t*B_ + bi)*2 + k];
        float pr = fmaf(sd, nz, mu);
        int o = (t*B_ + bi)*2 + k;
        out[o]          = pr;
        out[MU_OFF + o] = mu;
        out[SD_OFF + o] = sd;
        pos_s[i*2+k] += pr;
        prev_s[i*2+k] = pr;
      }
    }
    __syncthreads(); // E
  }
}

extern "C" void kernel_launch(void* const* d_in, const int* in_sizes, int n_in,
                              void* d_out, int out_size, void* d_ws, size_t ws_size,
                              hipStream_t stream) {
  (void)in_sizes; (void)n_in; (void)d_ws; (void)ws_size; (void)out_size;
  traj_ar_kernel<<<dim3(S_), dim3(256), 0, stream>>>(
      (const float*)d_in[0],  (const float*)d_in[1],  (const int*)d_in[2],   (const float*)d_in[3],
      (const float*)d_in[4],  (const float*)d_in[5],  (const float*)d_in[6], (const float*)d_in[7],
      (const float*)d_in[8],  (const float*)d_in[9],  (const float*)d_in[10],(const float*)d_in[11],
      (const float*)d_in[12], (const float*)d_in[13], (const float*)d_in[14],(const float*)d_in[15],
      (const float*)d_in[16], (const float*)d_in[17], (const float*)d_in[18],(const float*)d_in[19],
      (float*)d_out);
}

// Round 8
// 194.927 us; speedup vs baseline: 2.8462x; 1.1048x over previous
//
#include <hip/hip_runtime.h>

#define S_    2048
#define N_    16
#define OBS_  8
#define PRED_ 12
#define B_    (S_*N_)

typedef __attribute__((ext_vector_type(8))) short short8;
typedef __attribute__((ext_vector_type(4))) float floatx4;
typedef __attribute__((ext_vector_type(4))) unsigned uintx4;
typedef unsigned short ushort_t;

__device__ __forceinline__ float4 ld4(const float* p) { return *(const float4*)p; }
__device__ __forceinline__ float sigmf(float x) { return __builtin_amdgcn_rcpf(1.0f + __expf(-x)); }
__device__ __forceinline__ float tanhx(float x) { return fmaf(-2.0f, __builtin_amdgcn_rcpf(1.0f + __expf(2.0f*x)), 1.0f); }
// f32 -> bf16 RNE, pure bit ops
__device__ __forceinline__ unsigned f2bfu(float f) {
  unsigned u = __builtin_bit_cast(unsigned, f);
  return (u + 0x7FFFu + ((u >> 16) & 1u)) >> 16;
}
__device__ __forceinline__ unsigned pack2bf(float lo, float hi) {
  return f2bfu(lo) | (f2bfu(hi) << 16);
}

__device__ __forceinline__ float dot16w(const float* w, const float4 x0, const float4 x1,
                                        const float4 x2, const float4 x3) {
  float4 w0 = ld4(w); float4 w1 = ld4(w+4); float4 w2 = ld4(w+8); float4 w3 = ld4(w+12);
  float a = x0.x*w0.x + x0.y*w0.y + x0.z*w0.z + x0.w*w0.w;
  float b = x1.x*w1.x + x1.y*w1.y + x1.z*w1.z + x1.w*w1.w;
  float c = x2.x*w2.x + x2.y*w2.y + x2.z*w2.z + x2.w*w2.w;
  float d = x3.x*w3.x + x3.y*w3.y + x3.z*w3.z + x3.w*w3.w;
  return (a+b)+(c+d);
}

// one scene per block; thread (i = agent, k = hidden unit), 256 threads.
// SKELETON RULE (R2-R5 evidence): keep every barrier; change only phase bodies.
// Merging phases / removing barriers extends live ranges -> scratch spills ->
// 700-900 MB HBM traffic. Barriers are scheduling fences.
// R8: gate work distributed. Wave w computes ONLY gate-type w's 16x16 MFMA
// tile -> g_s; after barrier B each thread does the sigmoid/tanh elementwise
// for its own (agent,unit) pair (was 4x-redundant across waves in R7).
extern "C" __global__ __launch_bounds__(256, 4) void traj_ar_kernel(
    const float* __restrict__ traj_rel, const float* __restrict__ obs_pos,
    const int*  __restrict__ nei,       const float* __restrict__ noise,
    const float* __restrict__ eeW, const float* __restrict__ eeb,
    const float* __restrict__ eWi, const float* __restrict__ eWh, const float* __restrict__ eb,
    const float* __restrict__ diW, const float* __restrict__ dib,
    const float* __restrict__ dWi, const float* __restrict__ dWh, const float* __restrict__ db,
    const float* __restrict__ prW, const float* __restrict__ prb,
    const float* __restrict__ mW,  const float* __restrict__ mb,
    const float* __restrict__ oW,  const float* __restrict__ ob,
    float* __restrict__ out)
{
  // dec-in weights transposed, row stride 20 floats (80B, 2-way bank alias = free)
  __shared__ __align__(16) float sW_diT[16*20];   // 18 rows used of stride 20
  __shared__ __align__(16) float sb_di[16];
  __shared__ __align__(16) float sW_pr[32];
  __shared__ __align__(16) float sb_pr[16];
  __shared__ __align__(16) float sW_o[64];
  __shared__ __align__(16) float sb_o[4];
  // state
  __shared__ __align__(16) float h_s[256];        // f32 h, phase-5 input
  __shared__ __align__(16) float ctx_s[256];
  // gate tiles: plane gt = 256 floats, [agent*16 + unit]. b128 writes hit the
  // 8 words/bank floor; b32 reads at i*16+k are 64 consecutive words = 2/bank free.
  __shared__ __align__(16) float g_s[4*256];
  // bf16 activations, [agent][unit] stride 24 ushorts (48B: b128-aligned,
  // 12-word row starts cover 8 bank-quads; b128 reads land at the 8 words/bank floor)
  __shared__ __align__(16) ushort_t e_bf[16*24];
  __shared__ __align__(16) ushort_t hb_s[16*24];
  // pool embeddings bf16: [i][j] j-stride 24 ushorts, i-stride 392 (784B, 16B-aligned)
  __shared__ __align__(16) ushort_t re_s[16*392];
  __shared__ __align__(16) float pos_s[32];
  __shared__ __align__(16) float prev_s[32];
  __shared__            unsigned sm_s[16];   // neighbor mask bits per agent

  const int tid = threadIdx.x;
  const int s = blockIdx.x;
  const int i = tid >> 4;
  const int k = tid & 15;
  const int bi = s*N_ + i;
  const int lq = (tid & 63) >> 4;       // quad within wave
  const int lc = tid & 15;              // col within wave (== k)
  const int w  = tid >> 6;              // wave index == this wave's gate type

  // ---- stage small weights into LDS ----
  for (int idx = tid; idx < 288; idx += 256) { int m = idx >> 4, c = idx & 15; sW_diT[c*20+m] = diW[idx]; }
  if (tid < 16) sb_di[tid] = dib[tid];
  if (tid < 32) sW_pr[tid] = prW[tid];
  if (tid < 16) sb_pr[tid] = prb[tid];
  if (tid < 64) sW_o[tid] = oW[tid];
  if (tid < 4)  sb_o[tid] = ob[tid];
  if (tid < 192) ((unsigned*)hb_s)[tid] = 0;   // h0 = 0 for first encoder step

  ctx_s[tid] = 0.0f;
  if (k < 2) {
    prev_s[i*2+k] = traj_rel[((OBS_-1)*B_ + bi)*2 + k];  // out init = traj_rel[OBS-1]
    pos_s[i*2+k]  = obs_pos[((OBS_-1)*B_ + bi)*2 + k];   // pos init = obs_traj_pos[-1]
  }

  // pool-MLP B-fragment (32x16 bf16 weights) + bias
  short8 bfrag;
  {
    uintx4 bw;
    #pragma unroll
    for (int p = 0; p < 4; ++p)
      bw[p] = pack2bf(mW[(8*lq + 2*p)*16 + lc], mW[(8*lq + 2*p + 1)*16 + lc]);
    bfrag = __builtin_bit_cast(short8, bw);
  }
  floatx4 cinit;
  { float bm = mb[lc]; cinit[0]=bm; cinit[1]=bm; cinit[2]=bm; cinit[3]=bm; }

  // encoder embed weights per thread (unit k)
  const float w0k = eeW[k], w1k = eeW[16+k], bek = eeb[k];

  // encoder gate A-fragment for THIS wave's gate type w (weights, constant) + bias C.
  // A[m=unit=lc][kk=lq*8+j]: kk<16 -> Wi[kk][w*16+m], else Wh[kk-16][w*16+m]
  short8 gA; floatx4 gC;
  {
    const int row0 = (lq & 1) * 8;
    const float* gsrc = (lq & 2) ? eWh : eWi;
    uintx4 aw;
    #pragma unroll
    for (int p = 0; p < 4; ++p)
      aw[p] = pack2bf(gsrc[(row0+2*p)*64 + w*16 + lc], gsrc[(row0+2*p+1)*64 + w*16 + lc]);
    gA = __builtin_bit_cast(short8, aw);
    #pragma unroll
    for (int r = 0; r < 4; ++r) gC[r] = eb[w*16 + lq*4 + r];   // bias by D-row unit
  }

  // time-invariant neighbor mask -> per-agent bitmask in LDS
  unsigned long long bal = __ballot(nei[bi*N_ + k] > 0);
  if (k == 0) sm_s[i] = (unsigned)((bal >> (16*(i & 3))) & 0xFFFFull);

  __syncthreads();

  // ---- encoder: 8 LSTM steps, 2 barriers/step ----
  float c_reg = 0.0f;
  const float2* xr2 = (const float2*)traj_rel;
  for (int t = 0; t < OBS_; ++t) {
    // P1e: e[i][k] = relu(x @ eeW + b), bf16 to LDS
    {
      float2 x = xr2[t*B_ + bi];
      float e = fmaxf(fmaf(x.y, w1k, fmaf(x.x, w0k, bek)), 0.0f);
      e_bf[i*24 + k] = (ushort_t)f2bfu(e);
    }
    __syncthreads(); // A: e_bf ready; prev step's hb_s writes drained
    // P2a: this wave's gate-type MFMA -> g_s (D row = unit lq*4+r, col = agent lc)
    {
      const ushort_t* bp = (lq < 2) ? &e_bf[lc*24 + (lq&1)*8] : &hb_s[lc*24 + (lq&1)*8];
      short8 bfr = *(const short8*)bp;
      floatx4 d = __builtin_amdgcn_mfma_f32_16x16x32_bf16(gA, bfr, gC, 0, 0, 0);
      *(floatx4*)&g_s[w*256 + lc*16 + lq*4] = d;
    }
    __syncthreads(); // B: g_s ready; hb_s MFMA reads drained
    // P2b: distributed elementwise — thread (i,k) owns its (agent,unit) pair
    {
      float gI = g_s[0*256 + i*16 + k];
      float gF = g_s[1*256 + i*16 + k];
      float gG = g_s[2*256 + i*16 + k];
      float gO = g_s[3*256 + i*16 + k];
      float ig = sigmf(gI), fg = sigmf(gF), gv = tanhx(gG), og = sigmf(gO);
      c_reg = fg*c_reg + ig*gv;
      float nh = og * tanhx(c_reg);
      hb_s[i*24 + k] = (ushort_t)f2bfu(nh);
    }
  }

  // decoder gate A-fragment + bias (loaded after encoder: separate live ranges)
  short8 dA; floatx4 dC;
  {
    const int row0 = (lq & 1) * 8;
    const float* gsrc = (lq & 2) ? dWh : dWi;
    uintx4 aw;
    #pragma unroll
    for (int p = 0; p < 4; ++p)
      aw[p] = pack2bf(gsrc[(row0+2*p)*64 + w*16 + lc], gsrc[(row0+2*p+1)*64 + w*16 + lc]);
    dA = __builtin_bit_cast(short8, aw);
    #pragma unroll
    for (int r = 0; r < 4; ++r) dC[r] = db[w*16 + lq*4 + r];
  }

  // ---- decoder: 12 autoregressive steps, 5 barriers/step ----
  c_reg = 0.0f;                       // decoder c starts at zero
  const int MU_OFF = PRED_*B_*2;
  const int SD_OFF = 2*PRED_*B_*2;
  for (int t = 0; t < PRED_; ++t) {
    // phase 1: e = relu([ctx, prev] @ dec_in_W + b), bf16 to LDS
    {
      const float* cx = &ctx_s[i*16];
      float4 c0 = ld4(cx), c1 = ld4(cx+4), c2 = ld4(cx+8), c3 = ld4(cx+12);
      float p0 = prev_s[i*2+0], p1 = prev_s[i*2+1];
      const float* wd = &sW_diT[k*20];
      float acc = sb_di[k] + dot16w(wd, c0,c1,c2,c3) + p0*wd[16] + p1*wd[17];
      e_bf[i*24 + k] = (ushort_t)f2bfu(fmaxf(acc, 0.0f));
    }
    __syncthreads(); // A
    // phase 2a: this wave's gate-type MFMA -> g_s
    {
      const ushort_t* bp = (lq < 2) ? &e_bf[lc*24 + (lq&1)*8] : &hb_s[lc*24 + (lq&1)*8];
      short8 bfr = *(const short8*)bp;
      floatx4 d = __builtin_amdgcn_mfma_f32_16x16x32_bf16(dA, bfr, dC, 0, 0, 0);
      *(floatx4*)&g_s[w*256 + lc*16 + lq*4] = d;
    }
    __syncthreads(); // B: g_s ready; hb_s MFMA reads drained
    // phase 2b: distributed elementwise; write f32 h (phase 5) + bf16 h (pool/next gates)
    {
      float gI = g_s[0*256 + i*16 + k];
      float gF = g_s[1*256 + i*16 + k];
      float gG = g_s[2*256 + i*16 + k];
      float gO = g_s[3*256 + i*16 + k];
      float ig = sigmf(gI), fg = sigmf(gF), gv = tanhx(gG), og = sigmf(gO);
      c_reg = fg*c_reg + ig*gv;
      float nh = og * tanhx(c_reg);
      h_s[i*16 + k] = nh;
      hb_s[i*24 + k] = (ushort_t)f2bfu(nh);
    }
    // phase 3: re[i][j=k][:] = relu(rel @ prW + b), bf16 packed -> two b128 stores
    {
      float rx = pos_s[i*2+0] - pos_s[k*2+0];
      float ry = pos_s[i*2+1] - pos_s[k*2+1];
      uintx4 v0, v1;
      #pragma unroll
      for (int m = 0; m < 4; ++m) {
        float a0 = fmaxf(fmaf(ry, sW_pr[16+2*m], fmaf(rx, sW_pr[2*m],   sb_pr[2*m])),   0.0f);
        float a1 = fmaxf(fmaf(ry, sW_pr[17+2*m], fmaf(rx, sW_pr[2*m+1], sb_pr[2*m+1])), 0.0f);
        float b0 = fmaxf(fmaf(ry, sW_pr[24+2*m], fmaf(rx, sW_pr[8+2*m], sb_pr[8+2*m])), 0.0f);
        float b1 = fmaxf(fmaf(ry, sW_pr[25+2*m], fmaf(rx, sW_pr[9+2*m], sb_pr[9+2*m])), 0.0f);
        v0[m] = pack2bf(a0, a1);
        v1[m] = pack2bf(b0, b1);
      }
      uintx4* rp = (uintx4*)&re_s[i*392 + k*24];
      rp[0] = v0;
      rp[1] = v1;
    }
    __syncthreads(); // C: re_s + hb_s (from P2b) ready for pool
    // phase 4: masked max-pool via MFMA. Tile = agent it of this wave;
    // A[j][0:16]=re[it][j][:], A[j][16:32]=h[j][:]; D[j][k] -> masked max over j.
    {
      const ushort_t* hbp = &hb_s[lc*24 + (lq-2)*8];
      #pragma unroll
      for (int tt = 0; tt < 4; ++tt) {
        const int it = 4*w + tt;
        const ushort_t* rep = &re_s[it*392 + lc*24 + lq*8];
        const ushort_t* ap = (lq < 2) ? rep : hbp;
        short8 a = *(const short8*)ap;
        floatx4 d = __builtin_amdgcn_mfma_f32_16x16x32_bf16(a, bfrag, cinit, 0, 0, 0);
        const unsigned mi = sm_s[it];
        float pm = -1e30f;
        #pragma unroll
        for (int r = 0; r < 4; ++r) {
          float feat = fmaxf(d[r], 0.0f);            // row j = lq*4+r, col k = lc
          bool on = (mi >> (lq*4 + r)) & 1u;
          pm = on ? fmaxf(pm, feat) : pm;
        }
        pm = fmaxf(pm, __shfl_xor(pm, 16, 64));
        pm = fmaxf(pm, __shfl_xor(pm, 32, 64));
        if (lq == tt) ctx_s[it*16 + lc] = (mi != 0u) ? pm : 0.0f;  // quad tt owns tile tt
      }
    }
    __syncthreads(); // D
    // phase 5: o4 = (h+ctx)@out_W + b; mu/std/pred; write outputs; advance pos
    {
      float o4v = 0.0f;
      if (k < 4) {
        const float* hp = &h_s[i*16];
        const float* cx = &ctx_s[i*16];
        float acc = sb_o[k];
        #pragma unroll
        for (int m = 0; m < 16; ++m) acc = fmaf(hp[m]+cx[m], sW_o[m*4+k], acc);
        o4v = acc;
      }
      float sc = __shfl_down(o4v, 2, 64);   // lane k<2 grabs o4[2+k]
      if (k < 2) {
        float mu = o4v;
        float scale = fminf(fmaxf(sc, -9.0f), 4.0f);
        float sd = __expf(scale);
        float nz = noise[(t*B_ + bi)*2 + k];
        float pr = fmaf(sd, nz, mu);
        int o = (t*B_ + bi)*2 + k;
        out[o]          = pr;
        out[MU_OFF + o] = mu;
        out[SD_OFF + o] = sd;
        pos_s[i*2+k] += pr;
        prev_s[i*2+k] = pr;
      }
    }
    __syncthreads(); // E
  }
}

extern "C" void kernel_launch(void* const* d_in, const int* in_sizes, int n_in,
                              void* d_out, int out_size, void* d_ws, size_t ws_size,
                              hipStream_t stream) {
  (void)in_sizes; (void)n_in; (void)d_ws; (void)ws_size; (void)out_size;
  traj_ar_kernel<<<dim3(S_), dim3(256), 0, stream>>>(
      (const float*)d_in[0],  (const float*)d_in[1],  (const int*)d_in[2],   (const float*)d_in[3],
      (const float*)d_in[4],  (const float*)d_in[5],  (const float*)d_in[6], (const float*)d_in[7],
      (const float*)d_in[8],  (const float*)d_in[9],  (const float*)d_in[10],(const float*)d_in[11],
      (const float*)d_in[12], (const float*)d_in[13], (const float*)d_in[14],(const float*)d_in[15],
      (const float*)d_in[16], (const float*)d_in[17], (const float*)d_in[18],(const float*)d_in[19],
      (float*)d_out);
}

// Round 9
// 182.341 us; speedup vs baseline: 3.0426x; 1.0690x over previous
//
#include <hip/hip_runtime.h>

#define S_    2048
#define N_    16
#define OBS_  8
#define PRED_ 12
#define B_    (S_*N_)

typedef __attribute__((ext_vector_type(8))) short short8;
typedef __attribute__((ext_vector_type(4))) float floatx4;
typedef __attribute__((ext_vector_type(4))) unsigned uintx4;
typedef unsigned short ushort_t;

__device__ __forceinline__ float4 ld4(const float* p) { return *(const float4*)p; }
__device__ __forceinline__ float sigmf(float x) { return __builtin_amdgcn_rcpf(1.0f + __expf(-x)); }
__device__ __forceinline__ float tanhx(float x) { return fmaf(-2.0f, __builtin_amdgcn_rcpf(1.0f + __expf(2.0f*x)), 1.0f); }
// f32 -> bf16 round-half-up: bits+0x8000, truncate. <=0.5 ulp like RNE (ties differ only).
// 1 v_add per value + 1 v_perm per pair vs ~4 ops/value for full RNE.
__device__ __forceinline__ unsigned bfhi(float f) {
  return __builtin_bit_cast(unsigned, f) + 0x8000u;
}
__device__ __forceinline__ unsigned pack2bf(float lo, float hi) {
  return __builtin_amdgcn_perm(bfhi(hi), bfhi(lo), 0x07060302);  // [hi.b3,hi.b2,lo.b3,lo.b2]
}
__device__ __forceinline__ ushort_t f2bf1(float f) { return (ushort_t)(bfhi(f) >> 16); }

__device__ __forceinline__ float dot16w(const float* w, const float4 x0, const float4 x1,
                                        const float4 x2, const float4 x3) {
  float4 w0 = ld4(w); float4 w1 = ld4(w+4); float4 w2 = ld4(w+8); float4 w3 = ld4(w+12);
  float a = x0.x*w0.x + x0.y*w0.y + x0.z*w0.z + x0.w*w0.w;
  float b = x1.x*w1.x + x1.y*w1.y + x1.z*w1.z + x1.w*w1.w;
  float c = x2.x*w2.x + x2.y*w2.y + x2.z*w2.z + x2.w*w2.w;
  float d = x3.x*w3.x + x3.y*w3.y + x3.z*w3.z + x3.w*w3.w;
  return (a+b)+(c+d);
}

// one scene per block; thread (i = agent, k = hidden unit), 256 threads.
// SKELETON RULE (R2-R5 evidence): keep every barrier; change only phase bodies.
// Merging phases / removing barriers extends live ranges -> scratch spills ->
// 700-900 MB HBM traffic. Barriers are scheduling fences.
// R9: (a) cheap bf16 pack (+0x8000 & v_perm); (b) pool mask baked into MFMA
// C-operand (-1e9 rows; valid because feats are post-relu >= 0, so masked-0
// and the all-masked case fall out of relu(max)); (c) early noise load.
extern "C" __global__ __launch_bounds__(256, 4) void traj_ar_kernel(
    const float* __restrict__ traj_rel, const float* __restrict__ obs_pos,
    const int*  __restrict__ nei,       const float* __restrict__ noise,
    const float* __restrict__ eeW, const float* __restrict__ eeb,
    const float* __restrict__ eWi, const float* __restrict__ eWh, const float* __restrict__ eb,
    const float* __restrict__ diW, const float* __restrict__ dib,
    const float* __restrict__ dWi, const float* __restrict__ dWh, const float* __restrict__ db,
    const float* __restrict__ prW, const float* __restrict__ prb,
    const float* __restrict__ mW,  const float* __restrict__ mb,
    const float* __restrict__ oW,  const float* __restrict__ ob,
    float* __restrict__ out)
{
  // dec-in weights transposed, row stride 20 floats (80B, 2-way bank alias = free)
  __shared__ __align__(16) float sW_diT[16*20];   // 18 rows used of stride 20
  __shared__ __align__(16) float sb_di[16];
  __shared__ __align__(16) float sW_pr[32];
  __shared__ __align__(16) float sb_pr[16];
  __shared__ __align__(16) float sW_o[64];
  __shared__ __align__(16) float sb_o[4];
  // state
  __shared__ __align__(16) float h_s[256];        // f32 h, phase-5 input
  __shared__ __align__(16) float ctx_s[256];
  // gate tiles: plane gt = 256 floats, [agent*16 + unit]. b128 writes hit the
  // 8 words/bank floor; b32 reads at i*16+k are 64 consecutive words = 2/bank free.
  __shared__ __align__(16) float g_s[4*256];
  // bf16 activations, [agent][unit] stride 24 ushorts (48B: b128-aligned,
  // 12-word row starts cover 8 bank-quads; b128 reads land at the 8 words/bank floor)
  __shared__ __align__(16) ushort_t e_bf[16*24];
  __shared__ __align__(16) ushort_t hb_s[16*24];
  // pool embeddings bf16: [i][j] j-stride 24 ushorts, i-stride 392 (784B, 16B-aligned)
  __shared__ __align__(16) ushort_t re_s[16*392];
  __shared__ __align__(16) float pos_s[32];
  __shared__ __align__(16) float prev_s[32];
  __shared__            unsigned sm_s[16];   // neighbor mask bits per agent

  const int tid = threadIdx.x;
  const int s = blockIdx.x;
  const int i = tid >> 4;
  const int k = tid & 15;
  const int bi = s*N_ + i;
  const int lq = (tid & 63) >> 4;       // quad within wave
  const int lc = tid & 15;              // col within wave (== k)
  const int w  = tid >> 6;              // wave index == this wave's gate type

  // ---- stage small weights into LDS ----
  for (int idx = tid; idx < 288; idx += 256) { int m = idx >> 4, c = idx & 15; sW_diT[c*20+m] = diW[idx]; }
  if (tid < 16) sb_di[tid] = dib[tid];
  if (tid < 32) sW_pr[tid] = prW[tid];
  if (tid < 16) sb_pr[tid] = prb[tid];
  if (tid < 64) sW_o[tid] = oW[tid];
  if (tid < 4)  sb_o[tid] = ob[tid];
  if (tid < 192) ((unsigned*)hb_s)[tid] = 0;   // h0 = 0 for first encoder step

  ctx_s[tid] = 0.0f;
  if (k < 2) {
    prev_s[i*2+k] = traj_rel[((OBS_-1)*B_ + bi)*2 + k];  // out init = traj_rel[OBS-1]
    pos_s[i*2+k]  = obs_pos[((OBS_-1)*B_ + bi)*2 + k];   // pos init = obs_traj_pos[-1]
  }

  // pool-MLP B-fragment (32x16 bf16 weights)
  short8 bfrag;
  {
    uintx4 bw;
    #pragma unroll
    for (int p = 0; p < 4; ++p)
      bw[p] = pack2bf(mW[(8*lq + 2*p)*16 + lc], mW[(8*lq + 2*p + 1)*16 + lc]);
    bfrag = __builtin_bit_cast(short8, bw);
  }
  const float bm = mb[lc];

  // encoder embed weights per thread (unit k)
  const float w0k = eeW[k], w1k = eeW[16+k], bek = eeb[k];

  // encoder gate A-fragment for THIS wave's gate type w (weights, constant) + bias C.
  short8 gA; floatx4 gC;
  {
    const int row0 = (lq & 1) * 8;
    const float* gsrc = (lq & 2) ? eWh : eWi;
    uintx4 aw;
    #pragma unroll
    for (int p = 0; p < 4; ++p)
      aw[p] = pack2bf(gsrc[(row0+2*p)*64 + w*16 + lc], gsrc[(row0+2*p+1)*64 + w*16 + lc]);
    gA = __builtin_bit_cast(short8, aw);
    #pragma unroll
    for (int r = 0; r < 4; ++r) gC[r] = eb[w*16 + lq*4 + r];   // bias by D-row unit
  }

  // time-invariant neighbor mask -> per-agent bitmask in LDS
  unsigned long long bal = __ballot(nei[bi*N_ + k] > 0);
  if (k == 0) sm_s[i] = (unsigned)((bal >> (16*(i & 3))) & 0xFFFFull);

  __syncthreads();

  // ---- encoder: 8 LSTM steps, 2 barriers/step ----
  float c_reg = 0.0f;
  const float2* xr2 = (const float2*)traj_rel;
  for (int t = 0; t < OBS_; ++t) {
    // P1e: e[i][k] = relu(x @ eeW + b), bf16 to LDS
    {
      float2 x = xr2[t*B_ + bi];
      float e = fmaxf(fmaf(x.y, w1k, fmaf(x.x, w0k, bek)), 0.0f);
      e_bf[i*24 + k] = f2bf1(e);
    }
    __syncthreads(); // A: e_bf ready; prev step's hb_s writes drained
    // P2a: this wave's gate-type MFMA -> g_s (D row = unit lq*4+r, col = agent lc)
    {
      const ushort_t* bp = (lq < 2) ? &e_bf[lc*24 + (lq&1)*8] : &hb_s[lc*24 + (lq&1)*8];
      short8 bfr = *(const short8*)bp;
      floatx4 d = __builtin_amdgcn_mfma_f32_16x16x32_bf16(gA, bfr, gC, 0, 0, 0);
      *(floatx4*)&g_s[w*256 + lc*16 + lq*4] = d;
    }
    __syncthreads(); // B: g_s ready; hb_s MFMA reads drained
    // P2b: distributed elementwise — thread (i,k) owns its (agent,unit) pair
    {
      float gI = g_s[0*256 + i*16 + k];
      float gF = g_s[1*256 + i*16 + k];
      float gG = g_s[2*256 + i*16 + k];
      float gO = g_s[3*256 + i*16 + k];
      float ig = sigmf(gI), fg = sigmf(gF), gv = tanhx(gG), og = sigmf(gO);
      c_reg = fg*c_reg + ig*gv;
      float nh = og * tanhx(c_reg);
      hb_s[i*24 + k] = f2bf1(nh);
    }
  }

  // decoder gate A-fragment + bias (loaded after encoder: separate live ranges)
  short8 dA; floatx4 dC;
  {
    const int row0 = (lq & 1) * 8;
    const float* gsrc = (lq & 2) ? dWh : dWi;
    uintx4 aw;
    #pragma unroll
    for (int p = 0; p < 4; ++p)
      aw[p] = pack2bf(gsrc[(row0+2*p)*64 + w*16 + lc], gsrc[(row0+2*p+1)*64 + w*16 + lc]);
    dA = __builtin_bit_cast(short8, aw);
    #pragma unroll
    for (int r = 0; r < 4; ++r) dC[r] = db[w*16 + lq*4 + r];
  }

  // pool C-operands with mask baked in (time-invariant): tile tt's C[r] =
  // mask(4w+tt, row lq*4+r) ? mb[lc] : -1e9  -> relu(max) handles masked & all-masked.
  floatx4 cm0, cm1, cm2, cm3;
  {
    #pragma unroll
    for (int tt = 0; tt < 4; ++tt) {
      const unsigned mi = sm_s[4*w + tt];
      floatx4 cf;
      #pragma unroll
      for (int r = 0; r < 4; ++r)
        cf[r] = ((mi >> (lq*4 + r)) & 1u) ? bm : -1e9f;
      if (tt==0) cm0=cf; else if (tt==1) cm1=cf; else if (tt==2) cm2=cf; else cm3=cf;
    }
  }

  // ---- decoder: 12 autoregressive steps, 5 barriers/step ----
  c_reg = 0.0f;                       // decoder c starts at zero
  const int MU_OFF = PRED_*B_*2;
  const int SD_OFF = 2*PRED_*B_*2;
  for (int t = 0; t < PRED_; ++t) {
    // early noise load: consumed in phase 5, ~4 phases of latency hiding.
    // (k&1) keeps all lanes in bounds; only k<2 lanes use the value.
    const float nz = noise[(t*B_ + bi)*2 + (k & 1)];
    // phase 1: e = relu([ctx, prev] @ dec_in_W + b), bf16 to LDS
    {
      const float* cx = &ctx_s[i*16];
      float4 c0 = ld4(cx), c1 = ld4(cx+4), c2 = ld4(cx+8), c3 = ld4(cx+12);
      float p0 = prev_s[i*2+0], p1 = prev_s[i*2+1];
      const float* wd = &sW_diT[k*20];
      float acc = sb_di[k] + dot16w(wd, c0,c1,c2,c3) + p0*wd[16] + p1*wd[17];
      e_bf[i*24 + k] = f2bf1(fmaxf(acc, 0.0f));
    }
    __syncthreads(); // A
    // phase 2a: this wave's gate-type MFMA -> g_s
    {
      const ushort_t* bp = (lq < 2) ? &e_bf[lc*24 + (lq&1)*8] : &hb_s[lc*24 + (lq&1)*8];
      short8 bfr = *(const short8*)bp;
      floatx4 d = __builtin_amdgcn_mfma_f32_16x16x32_bf16(dA, bfr, dC, 0, 0, 0);
      *(floatx4*)&g_s[w*256 + lc*16 + lq*4] = d;
    }
    __syncthreads(); // B: g_s ready; hb_s MFMA reads drained
    // phase 2b: distributed elementwise; write f32 h (phase 5) + bf16 h (pool/next gates)
    {
      float gI = g_s[0*256 + i*16 + k];
      float gF = g_s[1*256 + i*16 + k];
      float gG = g_s[2*256 + i*16 + k];
      float gO = g_s[3*256 + i*16 + k];
      float ig = sigmf(gI), fg = sigmf(gF), gv = tanhx(gG), og = sigmf(gO);
      c_reg = fg*c_reg + ig*gv;
      float nh = og * tanhx(c_reg);
      h_s[i*16 + k] = nh;
      hb_s[i*24 + k] = f2bf1(nh);
    }
    // phase 3: re[i][j=k][:] = relu(rel @ prW + b), bf16 packed -> two b128 stores
    {
      float rx = pos_s[i*2+0] - pos_s[k*2+0];
      float ry = pos_s[i*2+1] - pos_s[k*2+1];
      uintx4 v0, v1;
      #pragma unroll
      for (int m = 0; m < 4; ++m) {
        float a0 = fmaxf(fmaf(ry, sW_pr[16+2*m], fmaf(rx, sW_pr[2*m],   sb_pr[2*m])),   0.0f);
        float a1 = fmaxf(fmaf(ry, sW_pr[17+2*m], fmaf(rx, sW_pr[2*m+1], sb_pr[2*m+1])), 0.0f);
        float b0 = fmaxf(fmaf(ry, sW_pr[24+2*m], fmaf(rx, sW_pr[8+2*m], sb_pr[8+2*m])), 0.0f);
        float b1 = fmaxf(fmaf(ry, sW_pr[25+2*m], fmaf(rx, sW_pr[9+2*m], sb_pr[9+2*m])), 0.0f);
        v0[m] = pack2bf(a0, a1);
        v1[m] = pack2bf(b0, b1);
      }
      uintx4* rp = (uintx4*)&re_s[i*392 + k*24];
      rp[0] = v0;
      rp[1] = v1;
    }
    __syncthreads(); // C: re_s + hb_s (from P2b) ready for pool
    // phase 4: masked max-pool via MFMA with mask-baked C; pooled = relu(max over 16 rows)
    {
      const ushort_t* hbp = &hb_s[lc*24 + (lq-2)*8];
      #pragma unroll
      for (int tt = 0; tt < 4; ++tt) {
        const int it = 4*w + tt;
        const ushort_t* rep = &re_s[it*392 + lc*24 + lq*8];
        const ushort_t* ap = (lq < 2) ? rep : hbp;
        short8 a = *(const short8*)ap;
        const floatx4 cm = (tt==0)?cm0:(tt==1)?cm1:(tt==2)?cm2:cm3;
        floatx4 d = __builtin_amdgcn_mfma_f32_16x16x32_bf16(a, bfrag, cm, 0, 0, 0);
        float pm = fmaxf(fmaxf(d[0], d[1]), fmaxf(d[2], d[3]));
        pm = fmaxf(pm, __shfl_xor(pm, 16, 64));
        pm = fmaxf(pm, __shfl_xor(pm, 32, 64));
        if (lq == tt) ctx_s[it*16 + lc] = fmaxf(pm, 0.0f);  // quad tt owns tile tt
      }
    }
    __syncthreads(); // D
    // phase 5: o4 = (h+ctx)@out_W + b; mu/std/pred; write outputs; advance pos
    {
      float o4v = 0.0f;
      if (k < 4) {
        const float* hp = &h_s[i*16];
        const float* cx = &ctx_s[i*16];
        float acc = sb_o[k];
        #pragma unroll
        for (int m = 0; m < 16; ++m) acc = fmaf(hp[m]+cx[m], sW_o[m*4+k], acc);
        o4v = acc;
      }
      float sc = __shfl_down(o4v, 2, 64);   // lane k<2 grabs o4[2+k]
      if (k < 2) {
        float mu = o4v;
        float scale = fminf(fmaxf(sc, -9.0f), 4.0f);
        float sd = __expf(scale);
        float pr = fmaf(sd, nz, mu);
        int o = (t*B_ + bi)*2 + k;
        out[o]          = pr;
        out[MU_OFF + o] = mu;
        out[SD_OFF + o] = sd;
        pos_s[i*2+k] += pr;
        prev_s[i*2+k] = pr;
      }
    }
    __syncthreads(); // E
  }
}

extern "C" void kernel_launch(void* const* d_in, const int* in_sizes, int n_in,
                              void* d_out, int out_size, void* d_ws, size_t ws_size,
                              hipStream_t stream) {
  (void)in_sizes; (void)n_in; (void)d_ws; (void)ws_size; (void)out_size;
  traj_ar_kernel<<<dim3(S_), dim3(256), 0, stream>>>(
      (const float*)d_in[0],  (const float*)d_in[1],  (const int*)d_in[2],   (const float*)d_in[3],
      (const float*)d_in[4],  (const float*)d_in[5],  (const float*)d_in[6], (const float*)d_in[7],
      (const float*)d_in[8],  (const float*)d_in[9],  (const float*)d_in[10],(const float*)d_in[11],
      (const float*)d_in[12], (const float*)d_in[13], (const float*)d_in[14],(const float*)d_in[15],
      (const float*)d_in[16], (const float*)d_in[17], (const float*)d_in[18],(const float*)d_in[19],
      (float*)d_out);
}